// Round 2
// baseline (1101.302 us; speedup 1.0000x reference)
//
#include <hip/hip_runtime.h>
#include <math.h>

#define N_NODES 100000
#define N_EDGES 3200000
#define F_INPUT 128
#define H1DIM 32
#define H2DIM 64
#define NGRAPH 256
#define NACT 64
#define SCAN_CHUNK 1024
#define BUCKET_SHIFT 6
#define NBUCK ((N_NODES + 63) / 64)   // 1563

// ---------------- CSR build ----------------
__global__ void hist_kernel(const int* __restrict__ dst, int* __restrict__ cnt, int e)
{
    int i = blockIdx.x * blockDim.x + threadIdx.x;
    int base = i * 4;
    if (base + 4 <= e) {
        int4 d = ((const int4*)dst)[i];
        atomicAdd(&cnt[d.x], 1);
        atomicAdd(&cnt[d.y], 1);
        atomicAdd(&cnt[d.z], 1);
        atomicAdd(&cnt[d.w], 1);
    } else {
        for (int j = base; j < e; ++j) atomicAdd(&cnt[dst[j]], 1);
    }
}

__global__ void scan_partial_kernel(const int* __restrict__ cnt, int* __restrict__ partial, int n)
{
    __shared__ int sdata[256];
    int base = blockIdx.x * SCAN_CHUNK;
    int lim = min(base + SCAN_CHUNK, n);
    int local = 0;
    for (int i = base + threadIdx.x; i < lim; i += 256) local += cnt[i];
    sdata[threadIdx.x] = local;
    __syncthreads();
    for (int off = 128; off > 0; off >>= 1) {
        if (threadIdx.x < off) sdata[threadIdx.x] += sdata[threadIdx.x + off];
        __syncthreads();
    }
    if (threadIdx.x == 0) partial[blockIdx.x] = sdata[0];
}

__global__ void scan_top_kernel(int* partial, int nb, int* rowptr, int n)
{
    int run = 0;
    for (int i = 0; i < nb; ++i) { int v = partial[i]; partial[i] = run; run += v; }
    rowptr[n] = run;
}

__global__ void scan_final_kernel(const int* __restrict__ cnt, const int* __restrict__ partial,
                                  int* __restrict__ rowptr, int* __restrict__ cursor,
                                  int* __restrict__ bucketCur,
                                  float* __restrict__ dinv, int n)
{
    __shared__ int s[256];
    int t = threadIdx.x;
    int base = blockIdx.x * SCAN_CHUNK + t * 4;
    int c0 = 0, c1 = 0, c2 = 0, c3 = 0;
    if (base + 0 < n) c0 = cnt[base + 0];
    if (base + 1 < n) c1 = cnt[base + 1];
    if (base + 2 < n) c2 = cnt[base + 2];
    if (base + 3 < n) c3 = cnt[base + 3];
    int tsum = c0 + c1 + c2 + c3;
    s[t] = tsum;
    __syncthreads();
    for (int off = 1; off < 256; off <<= 1) {
        int v = (t >= off) ? s[t - off] : 0;
        __syncthreads();
        s[t] += v;
        __syncthreads();
    }
    int excl = s[t] - tsum;
    int run = partial[blockIdx.x] + excl;
    if (base + 0 < n) {
        if ((base & 63) == 0) bucketCur[base >> BUCKET_SHIFT] = run;  // seed bucket append cursor
        rowptr[base+0] = run; cursor[base+0] = run; dinv[base+0] = 1.0f / sqrtf((float)(c0 + 1)); run += c0;
    }
    if (base + 1 < n) { rowptr[base+1] = run; cursor[base+1] = run; dinv[base+1] = 1.0f / sqrtf((float)(c1 + 1)); run += c1; }
    if (base + 2 < n) { rowptr[base+2] = run; cursor[base+2] = run; dinv[base+2] = 1.0f / sqrtf((float)(c2 + 1)); run += c2; }
    if (base + 3 < n) { rowptr[base+3] = run; cursor[base+3] = run; dinv[base+3] = 1.0f / sqrtf((float)(c3 + 1)); run += c3; }
}

// Phase A: bin edges by dst>>6; dense append per bucket; pack (dstLocal<<17)|src in 4 bytes
__global__ void binA_kernel(const int* __restrict__ src, const int* __restrict__ dst,
                            int* __restrict__ bucketCur, int* __restrict__ binned, int e)
{
    int i = blockIdx.x * blockDim.x + threadIdx.x;
    if (i < e) {
        int d = dst[i];
        int s = src[i];
        int b = d >> BUCKET_SHIFT;
        int pos = atomicAdd(&bucketCur[b], 1);
        binned[pos] = ((d & 63) << 17) | s;
    }
}

// Phase B: per-bucket scatter into final CSR order (writes confined to bucket's region)
__global__ __launch_bounds__(256) void binB_kernel(const int* __restrict__ rowptr,
                                                   const int* __restrict__ binned,
                                                   int* __restrict__ cursor,
                                                   int* __restrict__ srcsorted, int n)
{
    int b = blockIdx.x;
    int nodeBeg = b << BUCKET_SHIFT;
    int nodeEnd = min(nodeBeg + 64, n);
    int beg = rowptr[nodeBeg];
    int end = rowptr[nodeEnd];
    for (int j = beg + threadIdx.x; j < end; j += 256) {
        int v = binned[j];
        int s = v & 0x1FFFF;
        int d = nodeBeg + (v >> 17);
        int pos = atomicAdd(&cursor[d], 1);
        srcsorted[pos] = s;
    }
}

// ---------------- tiled GEMM + per-row dinv scale ----------------
template<int KDIM, int NOUT>
__global__ __launch_bounds__(256) void gemm_scale_kernel(
    const float* __restrict__ x, const float* __restrict__ W,
    const float* __restrict__ dinv, float* __restrict__ out, int n)
{
    constexpr int ROWS = 64;
    constexpr int XS = KDIM + 4;
    constexpr int CG = NOUT / 8;
    constexpr int RPT = (ROWS * NOUT) / (256 * 8);
    __shared__ float xs[ROWS * XS];
    __shared__ float Ws[KDIM * NOUT];
    int t = threadIdx.x;
    int row0 = blockIdx.x * ROWS;

    for (int i = t; i < KDIM * NOUT; i += 256) Ws[i] = W[i];
    for (int i = t; i < ROWS * KDIM / 4; i += 256) {
        int r = i / (KDIM / 4);
        int kk = i % (KDIM / 4);
        float4 v = make_float4(0.f, 0.f, 0.f, 0.f);
        if (row0 + r < n) v = ((const float4*)x)[(size_t)(row0 + r) * (KDIM / 4) + kk];
        *(float4*)&xs[r * XS + kk * 4] = v;
    }
    __syncthreads();

    int tcg = t % CG;
    int trow = t / CG;
    float acc[RPT][8];
#pragma unroll
    for (int r = 0; r < RPT; ++r)
#pragma unroll
        for (int j = 0; j < 8; ++j) acc[r][j] = 0.f;

#pragma unroll
    for (int k = 0; k < KDIM; k += 4) {
        float4 xv[RPT];
#pragma unroll
        for (int r = 0; r < RPT; ++r)
            xv[r] = *(float4*)&xs[(trow + r * 32) * XS + k];
#pragma unroll
        for (int kk = 0; kk < 4; ++kk) {
            float4 w0 = *(float4*)&Ws[(k + kk) * NOUT + tcg * 8];
            float4 w1 = *(float4*)&Ws[(k + kk) * NOUT + tcg * 8 + 4];
#pragma unroll
            for (int r = 0; r < RPT; ++r) {
                float xk = ((float*)&xv[r])[kk];
                acc[r][0] += xk * w0.x; acc[r][1] += xk * w0.y;
                acc[r][2] += xk * w0.z; acc[r][3] += xk * w0.w;
                acc[r][4] += xk * w1.x; acc[r][5] += xk * w1.y;
                acc[r][6] += xk * w1.z; acc[r][7] += xk * w1.w;
            }
        }
    }

#pragma unroll
    for (int r = 0; r < RPT; ++r) {
        int row = row0 + trow + r * 32;
        if (row < n) {
            float dv = dinv[row];
            float4 o0 = make_float4(acc[r][0]*dv, acc[r][1]*dv, acc[r][2]*dv, acc[r][3]*dv);
            float4 o1 = make_float4(acc[r][4]*dv, acc[r][5]*dv, acc[r][6]*dv, acc[r][7]*dv);
            *(float4*)&out[(size_t)row * NOUT + tcg * 8]     = o0;
            *(float4*)&out[(size_t)row * NOUT + tcg * 8 + 4] = o1;
        }
    }
}

// ---------------- gather-side aggregation (float4 per thread) ----------------
template<int F, bool LEAKY>
__global__ __launch_bounds__(256) void agg_kernel(
    const float* __restrict__ tmp, const int* __restrict__ rowptr,
    const int* __restrict__ srcs, const float* __restrict__ dinv,
    const float* __restrict__ bias, float* __restrict__ out, int n)
{
    constexpr int FG = F / 4;
    int tid = blockIdx.x * blockDim.x + threadIdx.x;
    int node = tid / FG;
    int fg = tid % FG;
    if (node >= n) return;
    int beg = rowptr[node], end = rowptr[node + 1];
    const float4* t4 = (const float4*)tmp;
    float4 acc = t4[(size_t)node * FG + fg];   // self-loop
    int j = beg;
    for (; j + 4 <= end; j += 4) {
        int s0 = srcs[j], s1 = srcs[j + 1], s2 = srcs[j + 2], s3 = srcs[j + 3];
        float4 v0 = t4[(size_t)s0 * FG + fg];
        float4 v1 = t4[(size_t)s1 * FG + fg];
        float4 v2 = t4[(size_t)s2 * FG + fg];
        float4 v3 = t4[(size_t)s3 * FG + fg];
        acc.x += v0.x; acc.y += v0.y; acc.z += v0.z; acc.w += v0.w;
        acc.x += v1.x; acc.y += v1.y; acc.z += v1.z; acc.w += v1.w;
        acc.x += v2.x; acc.y += v2.y; acc.z += v2.z; acc.w += v2.w;
        acc.x += v3.x; acc.y += v3.y; acc.z += v3.z; acc.w += v3.w;
    }
    for (; j < end; ++j) {
        float4 v = t4[(size_t)srcs[j] * FG + fg];
        acc.x += v.x; acc.y += v.y; acc.z += v.z; acc.w += v.w;
    }
    float dv = dinv[node];
    float4 bb = ((const float4*)bias)[fg];
    float4 r;
    r.x = acc.x * dv + bb.x; r.y = acc.y * dv + bb.y;
    r.z = acc.z * dv + bb.z; r.w = acc.w * dv + bb.w;
    if (LEAKY) {
        r.x = (r.x > 0.f) ? r.x : 0.1f * r.x;
        r.y = (r.y > 0.f) ? r.y : 0.1f * r.y;
        r.z = (r.z > 0.f) ? r.z : 0.1f * r.z;
        r.w = (r.w > 0.f) ? r.w : 0.1f * r.w;
    }
    ((float4*)out)[(size_t)node * FG + fg] = r;
}

// ---------------- segment max over contiguous graphs ----------------
__global__ void segmax_kernel(const float* __restrict__ h2, float* __restrict__ g, int n, int ngraph)
{
    int gr = blockIdx.x;
    int f = threadIdx.x; // 64 threads
    int start = (gr * n + ngraph - 1) / ngraph;
    int end = ((gr + 1) * n + ngraph - 1) / ngraph;
    float m = -INFINITY;
    for (int i = start; i < end; ++i) m = fmaxf(m, h2[(size_t)i * H2DIM + f]);
    g[gr * H2DIM + f] = m;
}

// ---------------- tiny MLP head ----------------
__global__ __launch_bounds__(128) void mlp_kernel(
    const float* __restrict__ g,
    const float* __restrict__ l1W, const float* __restrict__ l1b,
    const float* __restrict__ l2W, const float* __restrict__ l2b,
    const float* __restrict__ l3W, const float* __restrict__ l3b,
    float* __restrict__ out)
{
    __shared__ float gin[64], z1[128], z2[64];
    int b = blockIdx.x, t = threadIdx.x;
    if (t < 64) gin[t] = g[b * 64 + t];
    __syncthreads();
    {
        float a = l1b[t];
        for (int k = 0; k < 64; ++k) a += gin[k] * l1W[k * 128 + t];
        z1[t] = (a > 0.f) ? a : 0.1f * a;
    }
    __syncthreads();
    if (t < 64) {
        float a = l2b[t];
        for (int k = 0; k < 128; ++k) a += z1[k] * l2W[k * 64 + t];
        z2[t] = (a > 0.f) ? a : 0.1f * a;
    }
    __syncthreads();
    if (t < 64) {
        float a = l3b[t];
        for (int k = 0; k < 64; ++k) a += z2[k] * l3W[k * 64 + t];
        out[b * 64 + t] = a;
    }
}

extern "C" void kernel_launch(void* const* d_in, const int* in_sizes, int n_in,
                              void* d_out, int out_size, void* d_ws, size_t ws_size,
                              hipStream_t stream) {
    const float* x   = (const float*)d_in[0];
    const int*   ei  = (const int*)d_in[1];
    const int*   src = ei;
    const int*   dst = ei + N_EDGES;
    const float* W1  = (const float*)d_in[3];
    const float* b1  = (const float*)d_in[4];
    const float* W2  = (const float*)d_in[5];
    const float* b2  = (const float*)d_in[6];
    const float* l1W = (const float*)d_in[7];
    const float* l1b = (const float*)d_in[8];
    const float* l2W = (const float*)d_in[9];
    const float* l2b = (const float*)d_in[10];
    const float* l3W = (const float*)d_in[11];
    const float* l3b = (const float*)d_in[12];
    float* outp = (float*)d_out;

    char* w = (char*)d_ws;
    size_t off = 0;
    auto alloc = [&](size_t bytes) { char* p = w + off; off += (bytes + 255) & ~(size_t)255; return p; };
    int*   cnt       = (int*)  alloc(N_NODES * sizeof(int));
    int*   rowptr    = (int*)  alloc((N_NODES + 1) * sizeof(int));
    int*   cursor    = (int*)  alloc(N_NODES * sizeof(int));
    float* dinv      = (float*)alloc(N_NODES * sizeof(float));
    int*   partial   = (int*)  alloc(512 * sizeof(int));
    int*   bucketCur = (int*)  alloc(NBUCK * sizeof(int));
    int*   srcsorted = (int*)  alloc(N_EDGES * sizeof(int));
    float* bufA      = (float*)alloc((size_t)N_NODES * 64 * sizeof(float)); // tmp1 then tmp2
    float* bufB      = (float*)alloc((size_t)N_NODES * 64 * sizeof(float)); // h1 then h2
    float* gbuf      = (float*)alloc(NGRAPH * H2DIM * sizeof(float));

    float* tmp1 = bufA;  // [N,32]
    float* h1   = bufB;  // [N,32]
    float* tmp2 = bufA;  // [N,64]
    float* h2   = bufB;  // [N,64]
    // binned overlays the upper half of bufA: dead before gemm2 writes tmp2,
    // and tmp1 only occupies the first N*32 floats of bufA.
    int*   binned = (int*)(bufA + (size_t)N_NODES * 32);

    const int NB = (N_NODES + SCAN_CHUNK - 1) / SCAN_CHUNK; // 98

    hipMemsetAsync(cnt, 0, N_NODES * sizeof(int), stream);
    hist_kernel<<<(N_EDGES / 4 + 255) / 256, 256, 0, stream>>>(dst, cnt, N_EDGES);
    scan_partial_kernel<<<NB, 256, 0, stream>>>(cnt, partial, N_NODES);
    scan_top_kernel<<<1, 1, 0, stream>>>(partial, NB, rowptr, N_NODES);
    scan_final_kernel<<<NB, 256, 0, stream>>>(cnt, partial, rowptr, cursor, bucketCur, dinv, N_NODES);
    binA_kernel<<<(N_EDGES + 255) / 256, 256, 0, stream>>>(src, dst, bucketCur, binned, N_EDGES);
    binB_kernel<<<NBUCK, 256, 0, stream>>>(rowptr, binned, cursor, srcsorted, N_NODES);

    gemm_scale_kernel<F_INPUT, H1DIM><<<(N_NODES + 63) / 64, 256, 0, stream>>>(x, W1, dinv, tmp1, N_NODES);
    agg_kernel<H1DIM, true><<<((size_t)N_NODES * (H1DIM/4) + 255) / 256, 256, 0, stream>>>(
        tmp1, rowptr, srcsorted, dinv, b1, h1, N_NODES);
    gemm_scale_kernel<H1DIM, H2DIM><<<(N_NODES + 63) / 64, 256, 0, stream>>>(h1, W2, dinv, tmp2, N_NODES);
    agg_kernel<H2DIM, false><<<((size_t)N_NODES * (H2DIM/4) + 255) / 256, 256, 0, stream>>>(
        tmp2, rowptr, srcsorted, dinv, b2, h2, N_NODES);

    segmax_kernel<<<NGRAPH, 64, 0, stream>>>(h2, gbuf, N_NODES, NGRAPH);
    mlp_kernel<<<NGRAPH, 128, 0, stream>>>(gbuf, l1W, l1b, l2W, l2b, l3W, l3b, outp);
}

// Round 4
// 684.499 us; speedup vs baseline: 1.6089x; 1.6089x over previous
//
#include <hip/hip_runtime.h>
#include <math.h>

#define N_NODES 100000
#define N_EDGES 3200000
#define F_INPUT 128
#define H1DIM 32
#define H2DIM 64
#define NGRAPH 256
#define NACT 64
#define SCAN_CHUNK 1024
#define NPART 8
#define NCHUNK 256
#define PART_SZ (N_NODES / NPART)   // 12500

// ---------------- CSR build ----------------
__global__ void hist_kernel(const int* __restrict__ dst, int* __restrict__ cnt, int e)
{
    int i = blockIdx.x * blockDim.x + threadIdx.x;
    int base = i * 4;
    if (base + 4 <= e) {
        int4 d = ((const int4*)dst)[i];
        atomicAdd(&cnt[d.x], 1);
        atomicAdd(&cnt[d.y], 1);
        atomicAdd(&cnt[d.z], 1);
        atomicAdd(&cnt[d.w], 1);
    } else {
        for (int j = base; j < e; ++j) atomicAdd(&cnt[dst[j]], 1);
    }
}

__global__ void scan_partial_kernel(const int* __restrict__ cnt, int* __restrict__ partial, int n)
{
    __shared__ int sdata[256];
    int base = blockIdx.x * SCAN_CHUNK;
    int lim = min(base + SCAN_CHUNK, n);
    int local = 0;
    for (int i = base + threadIdx.x; i < lim; i += 256) local += cnt[i];
    sdata[threadIdx.x] = local;
    __syncthreads();
    for (int off = 128; off > 0; off >>= 1) {
        if (threadIdx.x < off) sdata[threadIdx.x] += sdata[threadIdx.x + off];
        __syncthreads();
    }
    if (threadIdx.x == 0) partial[blockIdx.x] = sdata[0];
}

__global__ void scan_top_kernel(int* partial, int nb, int* rowptr, int n)
{
    int run = 0;
    for (int i = 0; i < nb; ++i) { int v = partial[i]; partial[i] = run; run += v; }
    rowptr[n] = run;
}

__global__ void scan_final_kernel(const int* __restrict__ cnt, const int* __restrict__ partial,
                                  int* __restrict__ rowptr, int* __restrict__ cursor,
                                  float* __restrict__ dinv, int n)
{
    __shared__ int s[256];
    int t = threadIdx.x;
    int base = blockIdx.x * SCAN_CHUNK + t * 4;
    int c0 = 0, c1 = 0, c2 = 0, c3 = 0;
    if (base + 0 < n) c0 = cnt[base + 0];
    if (base + 1 < n) c1 = cnt[base + 1];
    if (base + 2 < n) c2 = cnt[base + 2];
    if (base + 3 < n) c3 = cnt[base + 3];
    int tsum = c0 + c1 + c2 + c3;
    s[t] = tsum;
    __syncthreads();
    for (int off = 1; off < 256; off <<= 1) {
        int v = (t >= off) ? s[t - off] : 0;
        __syncthreads();
        s[t] += v;
        __syncthreads();
    }
    int excl = s[t] - tsum;
    int run = partial[blockIdx.x] + excl;
    if (base + 0 < n) { rowptr[base+0] = run; cursor[base+0] = run; dinv[base+0] = 1.0f / sqrtf((float)(c0 + 1)); run += c0; }
    if (base + 1 < n) { rowptr[base+1] = run; cursor[base+1] = run; dinv[base+1] = 1.0f / sqrtf((float)(c1 + 1)); run += c1; }
    if (base + 2 < n) { rowptr[base+2] = run; cursor[base+2] = run; dinv[base+2] = 1.0f / sqrtf((float)(c2 + 1)); run += c2; }
    if (base + 3 < n) { rowptr[base+3] = run; cursor[base+3] = run; dinv[base+3] = 1.0f / sqrtf((float)(c3 + 1)); run += c3; }
}

// Partitioned scatter: blockIdx%8 -> dst-range partition (rides round-robin
// workgroup->XCD dispatch so each partition's cursor+srcsorted region stays in
// ONE XCD's L2; lines fill fully before writeback). Correct under any mapping:
// each edge is claimed by exactly one (partition, chunk) block.
__global__ __launch_bounds__(256) void place_part_kernel(const int* __restrict__ src,
                                                         const int* __restrict__ dst,
                                                         int* __restrict__ cursor,
                                                         int* __restrict__ srcsorted, int e)
{
    int p = blockIdx.x & (NPART - 1);
    int c = blockIdx.x >> 3;
    int lo = p * PART_SZ;
    int hi = lo + PART_SZ;
    int ebeg = (int)((long long)c * e / NCHUNK);
    int eend = (int)((long long)(c + 1) * e / NCHUNK);
    for (int i = ebeg + threadIdx.x; i < eend; i += 256) {
        int d = dst[i];
        if (d >= lo && d < hi) {
            int pos = atomicAdd(&cursor[d], 1);
            srcsorted[pos] = src[i];
        }
    }
}

// ---------------- tiled GEMM + per-row dinv scale ----------------
template<int KDIM, int NOUT>
__global__ __launch_bounds__(256) void gemm_scale_kernel(
    const float* __restrict__ x, const float* __restrict__ W,
    const float* __restrict__ dinv, float* __restrict__ out, int n)
{
    constexpr int ROWS = 64;
    constexpr int XS = KDIM + 4;
    constexpr int CG = NOUT / 8;
    constexpr int RPT = (ROWS * NOUT) / (256 * 8);
    __shared__ float xs[ROWS * XS];
    __shared__ float Ws[KDIM * NOUT];
    int t = threadIdx.x;
    int row0 = blockIdx.x * ROWS;

    for (int i = t; i < KDIM * NOUT; i += 256) Ws[i] = W[i];
    for (int i = t; i < ROWS * KDIM / 4; i += 256) {
        int r = i / (KDIM / 4);
        int kk = i % (KDIM / 4);
        float4 v = make_float4(0.f, 0.f, 0.f, 0.f);
        if (row0 + r < n) v = ((const float4*)x)[(size_t)(row0 + r) * (KDIM / 4) + kk];
        *(float4*)&xs[r * XS + kk * 4] = v;
    }
    __syncthreads();

    int tcg = t % CG;
    int trow = t / CG;
    float acc[RPT][8];
#pragma unroll
    for (int r = 0; r < RPT; ++r)
#pragma unroll
        for (int j = 0; j < 8; ++j) acc[r][j] = 0.f;

#pragma unroll
    for (int k = 0; k < KDIM; k += 4) {
        float4 xv[RPT];
#pragma unroll
        for (int r = 0; r < RPT; ++r)
            xv[r] = *(float4*)&xs[(trow + r * 32) * XS + k];
#pragma unroll
        for (int kk = 0; kk < 4; ++kk) {
            float4 w0 = *(float4*)&Ws[(k + kk) * NOUT + tcg * 8];
            float4 w1 = *(float4*)&Ws[(k + kk) * NOUT + tcg * 8 + 4];
#pragma unroll
            for (int r = 0; r < RPT; ++r) {
                float xk = ((float*)&xv[r])[kk];
                acc[r][0] += xk * w0.x; acc[r][1] += xk * w0.y;
                acc[r][2] += xk * w0.z; acc[r][3] += xk * w0.w;
                acc[r][4] += xk * w1.x; acc[r][5] += xk * w1.y;
                acc[r][6] += xk * w1.z; acc[r][7] += xk * w1.w;
            }
        }
    }

#pragma unroll
    for (int r = 0; r < RPT; ++r) {
        int row = row0 + trow + r * 32;
        if (row < n) {
            float dv = dinv[row];
            float4 o0 = make_float4(acc[r][0]*dv, acc[r][1]*dv, acc[r][2]*dv, acc[r][3]*dv);
            float4 o1 = make_float4(acc[r][4]*dv, acc[r][5]*dv, acc[r][6]*dv, acc[r][7]*dv);
            *(float4*)&out[(size_t)row * NOUT + tcg * 8]     = o0;
            *(float4*)&out[(size_t)row * NOUT + tcg * 8 + 4] = o1;
        }
    }
}

// ---------------- gather-side aggregation (float4 per thread; proven) ----------------
template<int F, bool LEAKY>
__global__ __launch_bounds__(256) void agg_kernel(
    const float* __restrict__ tmp, const int* __restrict__ rowptr,
    const int* __restrict__ srcs, const float* __restrict__ dinv,
    const float* __restrict__ bias, float* __restrict__ out, int n)
{
    constexpr int FG = F / 4;
    int tid = blockIdx.x * blockDim.x + threadIdx.x;
    int node = tid / FG;
    int fg = tid % FG;
    if (node >= n) return;
    int beg = rowptr[node], end = rowptr[node + 1];
    const float4* t4 = (const float4*)tmp;
    float4 acc = t4[(size_t)node * FG + fg];   // self-loop
    int j = beg;
    for (; j + 4 <= end; j += 4) {
        int s0 = srcs[j], s1 = srcs[j + 1], s2 = srcs[j + 2], s3 = srcs[j + 3];
        float4 v0 = t4[(size_t)s0 * FG + fg];
        float4 v1 = t4[(size_t)s1 * FG + fg];
        float4 v2 = t4[(size_t)s2 * FG + fg];
        float4 v3 = t4[(size_t)s3 * FG + fg];
        acc.x += v0.x; acc.y += v0.y; acc.z += v0.z; acc.w += v0.w;
        acc.x += v1.x; acc.y += v1.y; acc.z += v1.z; acc.w += v1.w;
        acc.x += v2.x; acc.y += v2.y; acc.z += v2.z; acc.w += v2.w;
        acc.x += v3.x; acc.y += v3.y; acc.z += v3.z; acc.w += v3.w;
    }
    for (; j < end; ++j) {
        float4 v = t4[(size_t)srcs[j] * FG + fg];
        acc.x += v.x; acc.y += v.y; acc.z += v.z; acc.w += v.w;
    }
    float dv = dinv[node];
    float4 bb = ((const float4*)bias)[fg];
    float4 r;
    r.x = acc.x * dv + bb.x; r.y = acc.y * dv + bb.y;
    r.z = acc.z * dv + bb.z; r.w = acc.w * dv + bb.w;
    if (LEAKY) {
        r.x = (r.x > 0.f) ? r.x : 0.1f * r.x;
        r.y = (r.y > 0.f) ? r.y : 0.1f * r.y;
        r.z = (r.z > 0.f) ? r.z : 0.1f * r.z;
        r.w = (r.w > 0.f) ? r.w : 0.1f * r.w;
    }
    ((float4*)out)[(size_t)node * FG + fg] = r;
}

// ---------------- segment max over contiguous graphs ----------------
__global__ void segmax_kernel(const float* __restrict__ h2, float* __restrict__ g, int n, int ngraph)
{
    int gr = blockIdx.x;
    int f = threadIdx.x; // 64 threads
    int start = (gr * n + ngraph - 1) / ngraph;
    int end = ((gr + 1) * n + ngraph - 1) / ngraph;
    float m = -INFINITY;
    for (int i = start; i < end; ++i) m = fmaxf(m, h2[(size_t)i * H2DIM + f]);
    g[gr * H2DIM + f] = m;
}

// ---------------- tiny MLP head ----------------
__global__ __launch_bounds__(128) void mlp_kernel(
    const float* __restrict__ g,
    const float* __restrict__ l1W, const float* __restrict__ l1b,
    const float* __restrict__ l2W, const float* __restrict__ l2b,
    const float* __restrict__ l3W, const float* __restrict__ l3b,
    float* __restrict__ out)
{
    __shared__ float gin[64], z1[128], z2[64];
    int b = blockIdx.x, t = threadIdx.x;
    if (t < 64) gin[t] = g[b * 64 + t];
    __syncthreads();
    {
        float a = l1b[t];
        for (int k = 0; k < 64; ++k) a += gin[k] * l1W[k * 128 + t];
        z1[t] = (a > 0.f) ? a : 0.1f * a;
    }
    __syncthreads();
    if (t < 64) {
        float a = l2b[t];
        for (int k = 0; k < 128; ++k) a += z1[k] * l2W[k * 64 + t];
        z2[t] = (a > 0.f) ? a : 0.1f * a;
    }
    __syncthreads();
    if (t < 64) {
        float a = l3b[t];
        for (int k = 0; k < 64; ++k) a += z2[k] * l3W[k * 64 + t];
        out[b * 64 + t] = a;
    }
}

extern "C" void kernel_launch(void* const* d_in, const int* in_sizes, int n_in,
                              void* d_out, int out_size, void* d_ws, size_t ws_size,
                              hipStream_t stream) {
    const float* x   = (const float*)d_in[0];
    const int*   ei  = (const int*)d_in[1];
    const int*   src = ei;
    const int*   dst = ei + N_EDGES;
    const float* W1  = (const float*)d_in[3];
    const float* b1  = (const float*)d_in[4];
    const float* W2  = (const float*)d_in[5];
    const float* b2  = (const float*)d_in[6];
    const float* l1W = (const float*)d_in[7];
    const float* l1b = (const float*)d_in[8];
    const float* l2W = (const float*)d_in[9];
    const float* l2b = (const float*)d_in[10];
    const float* l3W = (const float*)d_in[11];
    const float* l3b = (const float*)d_in[12];
    float* outp = (float*)d_out;

    char* w = (char*)d_ws;
    size_t off = 0;
    auto alloc = [&](size_t bytes) { char* p = w + off; off += (bytes + 255) & ~(size_t)255; return p; };
    int*   cnt       = (int*)  alloc(N_NODES * sizeof(int));
    int*   rowptr    = (int*)  alloc((N_NODES + 1) * sizeof(int));
    int*   cursor    = (int*)  alloc(N_NODES * sizeof(int));
    float* dinv      = (float*)alloc(N_NODES * sizeof(float));
    int*   partial   = (int*)  alloc(512 * sizeof(int));
    int*   srcsorted = (int*)  alloc(N_EDGES * sizeof(int));
    float* bufA      = (float*)alloc((size_t)N_NODES * 64 * sizeof(float)); // tmp1 then tmp2
    float* bufB      = (float*)alloc((size_t)N_NODES * 64 * sizeof(float)); // h1 then h2
    float* gbuf      = (float*)alloc(NGRAPH * H2DIM * sizeof(float));

    float* tmp1 = bufA;  // [N,32]
    float* h1   = bufB;  // [N,32]
    float* tmp2 = bufA;  // [N,64]
    float* h2   = bufB;  // [N,64]

    const int NB = (N_NODES + SCAN_CHUNK - 1) / SCAN_CHUNK; // 98

    hipMemsetAsync(cnt, 0, N_NODES * sizeof(int), stream);
    hist_kernel<<<(N_EDGES / 4 + 255) / 256, 256, 0, stream>>>(dst, cnt, N_EDGES);
    scan_partial_kernel<<<NB, 256, 0, stream>>>(cnt, partial, N_NODES);
    scan_top_kernel<<<1, 1, 0, stream>>>(partial, NB, rowptr, N_NODES);
    scan_final_kernel<<<NB, 256, 0, stream>>>(cnt, partial, rowptr, cursor, dinv, N_NODES);
    place_part_kernel<<<NPART * NCHUNK, 256, 0, stream>>>(src, dst, cursor, srcsorted, N_EDGES);

    gemm_scale_kernel<F_INPUT, H1DIM><<<(N_NODES + 63) / 64, 256, 0, stream>>>(x, W1, dinv, tmp1, N_NODES);
    agg_kernel<H1DIM, true><<<((size_t)N_NODES * (H1DIM/4) + 255) / 256, 256, 0, stream>>>(
        tmp1, rowptr, srcsorted, dinv, b1, h1, N_NODES);
    gemm_scale_kernel<H1DIM, H2DIM><<<(N_NODES + 63) / 64, 256, 0, stream>>>(h1, W2, dinv, tmp2, N_NODES);
    agg_kernel<H2DIM, false><<<((size_t)N_NODES * (H2DIM/4) + 255) / 256, 256, 0, stream>>>(
        tmp2, rowptr, srcsorted, dinv, b2, h2, N_NODES);

    segmax_kernel<<<NGRAPH, 64, 0, stream>>>(h2, gbuf, N_NODES, NGRAPH);
    mlp_kernel<<<NGRAPH, 128, 0, stream>>>(gbuf, l1W, l1b, l2W, l2b, l3W, l3b, outp);
}

// Round 5
// 480.989 us; speedup vs baseline: 2.2897x; 1.4231x over previous
//
#include <hip/hip_runtime.h>
#include <math.h>

#define N_NODES 100000
#define N_EDGES 3200000
#define F_INPUT 128
#define H1DIM 32
#define H2DIM 64
#define NGRAPH 256
#define NACT 64
#define EPB 16384                          // edges per binning block
#define NBLK_A ((N_EDGES + EPB - 1) / EPB) // 196
#define NBUCK ((N_NODES + 255) / 256)      // 391 buckets of 256 dst nodes

// ---------------- CSR build: LDS-staged two-level binning ----------------
// A0: per-(block,bucket) histogram. No global atomics.
__global__ __launch_bounds__(256) void binhist_kernel(const int* __restrict__ dst,
                                                      int* __restrict__ countsA, int e)
{
    __shared__ int hist[NBUCK];
    for (int i = threadIdx.x; i < NBUCK; i += 256) hist[i] = 0;
    __syncthreads();
    int beg = blockIdx.x * EPB, end = min(beg + EPB, e);
    for (int i = beg + threadIdx.x; i < end; i += 256)
        atomicAdd(&hist[dst[i] >> 8], 1);
    __syncthreads();
    for (int i = threadIdx.x; i < NBUCK; i += 256)
        countsA[blockIdx.x * NBUCK + i] = hist[i];   // coalesced
}

// scanA: within-bucket exclusive scan over blocks + bucket bases. One block.
__global__ __launch_bounds__(512) void scanA_kernel(int* __restrict__ countsA,
                                                    int* __restrict__ bucketBase,
                                                    int* __restrict__ rowptr)
{
    __shared__ int sums[512];
    int b = threadIdx.x;
    int run = 0;
    if (b < NBUCK) {
        for (int blk = 0; blk < NBLK_A; ++blk) {       // loads coalesced across b
            int t = countsA[blk * NBUCK + b];
            countsA[blk * NBUCK + b] = run;            // within-bucket exclusive
            run += t;
        }
    }
    int own = (b < NBUCK) ? run : 0;
    sums[b] = own;
    __syncthreads();
    for (int off = 1; off < 512; off <<= 1) {
        int v = (b >= off) ? sums[b - off] : 0;
        __syncthreads();
        sums[b] += v;
        __syncthreads();
    }
    if (b < NBUCK) bucketBase[b] = sums[b] - own;      // exclusive bucket base
    if (b == 0) { bucketBase[NBUCK] = N_EDGES; rowptr[N_NODES] = N_EDGES; }
}

// A2: place packed edges into bucket-ordered `binned` via LDS cursors.
// Each (block,bucket) run is position-contiguous -> high line fill.
__global__ __launch_bounds__(256) void binplace_kernel(const int* __restrict__ src,
                                                       const int* __restrict__ dst,
                                                       const int* __restrict__ countsA,
                                                       const int* __restrict__ bucketBase,
                                                       int* __restrict__ binned, int e)
{
    __shared__ int cur[NBUCK];
    for (int i = threadIdx.x; i < NBUCK; i += 256)
        cur[i] = countsA[blockIdx.x * NBUCK + i] + bucketBase[i];
    __syncthreads();
    int beg = blockIdx.x * EPB, end = min(beg + EPB, e);
    for (int i = beg + threadIdx.x; i < end; i += 256) {
        int d = dst[i], s = src[i];
        int pos = atomicAdd(&cur[d >> 8], 1);          // LDS atomic
        binned[pos] = ((d & 255) << 17) | s;           // src<2^17, dstLocal<256
    }
}

// B: one block per bucket -> per-node counts, scan, dense scatter into the
// bucket's contiguous srcsorted region; emits rowptr & dinv.
__global__ __launch_bounds__(256) void csr_kernel(const int* __restrict__ binned,
                                                  const int* __restrict__ bucketBase,
                                                  int* __restrict__ srcsorted,
                                                  int* __restrict__ rowptr,
                                                  float* __restrict__ dinv, int n)
{
    __shared__ int hist[256];
    __shared__ int sc[256];
    int b = blockIdx.x, t = threadIdx.x;
    hist[t] = 0;
    __syncthreads();
    int eBeg = bucketBase[b], eEnd = bucketBase[b + 1];
    for (int i = eBeg + t; i < eEnd; i += 256)
        atomicAdd(&hist[binned[i] >> 17], 1);
    __syncthreads();
    int own = hist[t];
    sc[t] = own;
    __syncthreads();
    for (int off = 1; off < 256; off <<= 1) {
        int v = (t >= off) ? sc[t - off] : 0;
        __syncthreads();
        sc[t] += v;
        __syncthreads();
    }
    int excl = sc[t] - own;
    int node = b * 256 + t;
    if (node < n) {
        rowptr[node] = eBeg + excl;
        dinv[node] = 1.0f / sqrtf((float)(own + 1));   // deg incl. self-loop
    }
    hist[t] = eBeg + excl;                              // becomes cursor
    __syncthreads();
    for (int i = eBeg + t; i < eEnd; i += 256) {
        int v = binned[i];
        int pos = atomicAdd(&hist[v >> 17], 1);         // LDS atomic
        srcsorted[pos] = v & 0x1FFFF;                   // dense 32KB region
    }
}

// ---------------- tiled GEMM + per-row dinv scale (proven) ----------------
template<int KDIM, int NOUT>
__global__ __launch_bounds__(256) void gemm_scale_kernel(
    const float* __restrict__ x, const float* __restrict__ W,
    const float* __restrict__ dinv, float* __restrict__ out, int n)
{
    constexpr int ROWS = 64;
    constexpr int XS = KDIM + 4;
    constexpr int CG = NOUT / 8;
    constexpr int RPT = (ROWS * NOUT) / (256 * 8);
    __shared__ float xs[ROWS * XS];
    __shared__ float Ws[KDIM * NOUT];
    int t = threadIdx.x;
    int row0 = blockIdx.x * ROWS;

    for (int i = t; i < KDIM * NOUT; i += 256) Ws[i] = W[i];
    for (int i = t; i < ROWS * KDIM / 4; i += 256) {
        int r = i / (KDIM / 4);
        int kk = i % (KDIM / 4);
        float4 v = make_float4(0.f, 0.f, 0.f, 0.f);
        if (row0 + r < n) v = ((const float4*)x)[(size_t)(row0 + r) * (KDIM / 4) + kk];
        *(float4*)&xs[r * XS + kk * 4] = v;
    }
    __syncthreads();

    int tcg = t % CG;
    int trow = t / CG;
    float acc[RPT][8];
#pragma unroll
    for (int r = 0; r < RPT; ++r)
#pragma unroll
        for (int j = 0; j < 8; ++j) acc[r][j] = 0.f;

#pragma unroll
    for (int k = 0; k < KDIM; k += 4) {
        float4 xv[RPT];
#pragma unroll
        for (int r = 0; r < RPT; ++r)
            xv[r] = *(float4*)&xs[(trow + r * 32) * XS + k];
#pragma unroll
        for (int kk = 0; kk < 4; ++kk) {
            float4 w0 = *(float4*)&Ws[(k + kk) * NOUT + tcg * 8];
            float4 w1 = *(float4*)&Ws[(k + kk) * NOUT + tcg * 8 + 4];
#pragma unroll
            for (int r = 0; r < RPT; ++r) {
                float xk = ((float*)&xv[r])[kk];
                acc[r][0] += xk * w0.x; acc[r][1] += xk * w0.y;
                acc[r][2] += xk * w0.z; acc[r][3] += xk * w0.w;
                acc[r][4] += xk * w1.x; acc[r][5] += xk * w1.y;
                acc[r][6] += xk * w1.z; acc[r][7] += xk * w1.w;
            }
        }
    }

#pragma unroll
    for (int r = 0; r < RPT; ++r) {
        int row = row0 + trow + r * 32;
        if (row < n) {
            float dv = dinv[row];
            float4 o0 = make_float4(acc[r][0]*dv, acc[r][1]*dv, acc[r][2]*dv, acc[r][3]*dv);
            float4 o1 = make_float4(acc[r][4]*dv, acc[r][5]*dv, acc[r][6]*dv, acc[r][7]*dv);
            *(float4*)&out[(size_t)row * NOUT + tcg * 8]     = o0;
            *(float4*)&out[(size_t)row * NOUT + tcg * 8 + 4] = o1;
        }
    }
}

// ---------------- gather-side aggregation (float4 per thread; proven) ----------------
template<int F, bool LEAKY>
__global__ __launch_bounds__(256) void agg_kernel(
    const float* __restrict__ tmp, const int* __restrict__ rowptr,
    const int* __restrict__ srcs, const float* __restrict__ dinv,
    const float* __restrict__ bias, float* __restrict__ out, int n)
{
    constexpr int FG = F / 4;
    int tid = blockIdx.x * blockDim.x + threadIdx.x;
    int node = tid / FG;
    int fg = tid % FG;
    if (node >= n) return;
    int beg = rowptr[node], end = rowptr[node + 1];
    const float4* t4 = (const float4*)tmp;
    float4 acc = t4[(size_t)node * FG + fg];   // self-loop
    int j = beg;
    for (; j + 4 <= end; j += 4) {
        int s0 = srcs[j], s1 = srcs[j + 1], s2 = srcs[j + 2], s3 = srcs[j + 3];
        float4 v0 = t4[(size_t)s0 * FG + fg];
        float4 v1 = t4[(size_t)s1 * FG + fg];
        float4 v2 = t4[(size_t)s2 * FG + fg];
        float4 v3 = t4[(size_t)s3 * FG + fg];
        acc.x += v0.x; acc.y += v0.y; acc.z += v0.z; acc.w += v0.w;
        acc.x += v1.x; acc.y += v1.y; acc.z += v1.z; acc.w += v1.w;
        acc.x += v2.x; acc.y += v2.y; acc.z += v2.z; acc.w += v2.w;
        acc.x += v3.x; acc.y += v3.y; acc.z += v3.z; acc.w += v3.w;
    }
    for (; j < end; ++j) {
        float4 v = t4[(size_t)srcs[j] * FG + fg];
        acc.x += v.x; acc.y += v.y; acc.z += v.z; acc.w += v.w;
    }
    float dv = dinv[node];
    float4 bb = ((const float4*)bias)[fg];
    float4 r;
    r.x = acc.x * dv + bb.x; r.y = acc.y * dv + bb.y;
    r.z = acc.z * dv + bb.z; r.w = acc.w * dv + bb.w;
    if (LEAKY) {
        r.x = (r.x > 0.f) ? r.x : 0.1f * r.x;
        r.y = (r.y > 0.f) ? r.y : 0.1f * r.y;
        r.z = (r.z > 0.f) ? r.z : 0.1f * r.z;
        r.w = (r.w > 0.f) ? r.w : 0.1f * r.w;
    }
    ((float4*)out)[(size_t)node * FG + fg] = r;
}

// ---------------- segment max over contiguous graphs ----------------
__global__ void segmax_kernel(const float* __restrict__ h2, float* __restrict__ g, int n, int ngraph)
{
    int gr = blockIdx.x;
    int f = threadIdx.x; // 64 threads
    int start = (gr * n + ngraph - 1) / ngraph;
    int end = ((gr + 1) * n + ngraph - 1) / ngraph;
    float m = -INFINITY;
    for (int i = start; i < end; ++i) m = fmaxf(m, h2[(size_t)i * H2DIM + f]);
    g[gr * H2DIM + f] = m;
}

// ---------------- tiny MLP head ----------------
__global__ __launch_bounds__(128) void mlp_kernel(
    const float* __restrict__ g,
    const float* __restrict__ l1W, const float* __restrict__ l1b,
    const float* __restrict__ l2W, const float* __restrict__ l2b,
    const float* __restrict__ l3W, const float* __restrict__ l3b,
    float* __restrict__ out)
{
    __shared__ float gin[64], z1[128], z2[64];
    int b = blockIdx.x, t = threadIdx.x;
    if (t < 64) gin[t] = g[b * 64 + t];
    __syncthreads();
    {
        float a = l1b[t];
        for (int k = 0; k < 64; ++k) a += gin[k] * l1W[k * 128 + t];
        z1[t] = (a > 0.f) ? a : 0.1f * a;
    }
    __syncthreads();
    if (t < 64) {
        float a = l2b[t];
        for (int k = 0; k < 128; ++k) a += z1[k] * l2W[k * 64 + t];
        z2[t] = (a > 0.f) ? a : 0.1f * a;
    }
    __syncthreads();
    if (t < 64) {
        float a = l3b[t];
        for (int k = 0; k < 64; ++k) a += z2[k] * l3W[k * 64 + t];
        out[b * 64 + t] = a;
    }
}

extern "C" void kernel_launch(void* const* d_in, const int* in_sizes, int n_in,
                              void* d_out, int out_size, void* d_ws, size_t ws_size,
                              hipStream_t stream) {
    const float* x   = (const float*)d_in[0];
    const int*   ei  = (const int*)d_in[1];
    const int*   src = ei;
    const int*   dst = ei + N_EDGES;
    const float* W1  = (const float*)d_in[3];
    const float* b1  = (const float*)d_in[4];
    const float* W2  = (const float*)d_in[5];
    const float* b2  = (const float*)d_in[6];
    const float* l1W = (const float*)d_in[7];
    const float* l1b = (const float*)d_in[8];
    const float* l2W = (const float*)d_in[9];
    const float* l2b = (const float*)d_in[10];
    const float* l3W = (const float*)d_in[11];
    const float* l3b = (const float*)d_in[12];
    float* outp = (float*)d_out;

    char* w = (char*)d_ws;
    size_t off = 0;
    auto alloc = [&](size_t bytes) { char* p = w + off; off += (bytes + 255) & ~(size_t)255; return p; };
    int*   countsA    = (int*)  alloc((size_t)NBLK_A * NBUCK * sizeof(int)); // 306 KB
    int*   bucketBase = (int*)  alloc((NBUCK + 1) * sizeof(int));
    int*   rowptr     = (int*)  alloc((N_NODES + 1) * sizeof(int));
    float* dinv       = (float*)alloc(N_NODES * sizeof(float));
    int*   srcsorted  = (int*)  alloc(N_EDGES * sizeof(int));
    float* bufA       = (float*)alloc((size_t)N_NODES * 64 * sizeof(float)); // tmp1 then tmp2
    float* bufB       = (float*)alloc((size_t)N_NODES * 64 * sizeof(float)); // h1 then h2
    float* gbuf       = (float*)alloc(NGRAPH * H2DIM * sizeof(float));

    float* tmp1 = bufA;  // [N,32]
    float* h1   = bufB;  // [N,32]
    float* tmp2 = bufA;  // [N,64]
    float* h2   = bufB;  // [N,64]
    // binned (E ints = 12.8 MB) overlays upper half of bufA: dead before
    // gemm1/gemm2 need it (csr_kernel finishes first), and tmp1 = lower half.
    int* binned = (int*)(bufA + (size_t)N_NODES * 32);

    binhist_kernel<<<NBLK_A, 256, 0, stream>>>(dst, countsA, N_EDGES);
    scanA_kernel<<<1, 512, 0, stream>>>(countsA, bucketBase, rowptr);
    binplace_kernel<<<NBLK_A, 256, 0, stream>>>(src, dst, countsA, bucketBase, binned, N_EDGES);
    csr_kernel<<<NBUCK, 256, 0, stream>>>(binned, bucketBase, srcsorted, rowptr, dinv, N_NODES);

    gemm_scale_kernel<F_INPUT, H1DIM><<<(N_NODES + 63) / 64, 256, 0, stream>>>(x, W1, dinv, tmp1, N_NODES);
    agg_kernel<H1DIM, true><<<((size_t)N_NODES * (H1DIM/4) + 255) / 256, 256, 0, stream>>>(
        tmp1, rowptr, srcsorted, dinv, b1, h1, N_NODES);
    gemm_scale_kernel<H1DIM, H2DIM><<<(N_NODES + 63) / 64, 256, 0, stream>>>(h1, W2, dinv, tmp2, N_NODES);
    agg_kernel<H2DIM, false><<<((size_t)N_NODES * (H2DIM/4) + 255) / 256, 256, 0, stream>>>(
        tmp2, rowptr, srcsorted, dinv, b2, h2, N_NODES);

    segmax_kernel<<<NGRAPH, 64, 0, stream>>>(h2, gbuf, N_NODES, NGRAPH);
    mlp_kernel<<<NGRAPH, 128, 0, stream>>>(gbuf, l1W, l1b, l2W, l2b, l3W, l3b, outp);
}

// Round 6
// 402.094 us; speedup vs baseline: 2.7389x; 1.1962x over previous
//
#include <hip/hip_runtime.h>
#include <math.h>

#define N_NODES 100000
#define N_EDGES 3200000
#define F_INPUT 128
#define H1DIM 32
#define H2DIM 64
#define NGRAPH 256
#define NACT 64
#define EPB 16384                          // edges per binning block
#define NBLK_A ((N_EDGES + EPB - 1) / EPB) // 196
#define NBUCK ((N_NODES + 255) / 256)      // 391 buckets of 256 dst nodes

// ---------------- CSR build: LDS-staged two-level binning (proven R5) ----------------
__global__ __launch_bounds__(256) void binhist_kernel(const int* __restrict__ dst,
                                                      int* __restrict__ countsA, int e)
{
    __shared__ int hist[NBUCK];
    for (int i = threadIdx.x; i < NBUCK; i += 256) hist[i] = 0;
    __syncthreads();
    int beg = blockIdx.x * EPB, end = min(beg + EPB, e);
    for (int i = beg + threadIdx.x; i < end; i += 256)
        atomicAdd(&hist[dst[i] >> 8], 1);
    __syncthreads();
    for (int i = threadIdx.x; i < NBUCK; i += 256)
        countsA[blockIdx.x * NBUCK + i] = hist[i];   // coalesced
}

__global__ __launch_bounds__(512) void scanA_kernel(int* __restrict__ countsA,
                                                    int* __restrict__ bucketBase,
                                                    int* __restrict__ rowptr)
{
    __shared__ int sums[512];
    int b = threadIdx.x;
    int run = 0;
    if (b < NBUCK) {
        for (int blk = 0; blk < NBLK_A; ++blk) {
            int t = countsA[blk * NBUCK + b];
            countsA[blk * NBUCK + b] = run;
            run += t;
        }
    }
    int own = (b < NBUCK) ? run : 0;
    sums[b] = own;
    __syncthreads();
    for (int off = 1; off < 512; off <<= 1) {
        int v = (b >= off) ? sums[b - off] : 0;
        __syncthreads();
        sums[b] += v;
        __syncthreads();
    }
    if (b < NBUCK) bucketBase[b] = sums[b] - own;
    if (b == 0) { bucketBase[NBUCK] = N_EDGES; rowptr[N_NODES] = N_EDGES; }
}

__global__ __launch_bounds__(256) void binplace_kernel(const int* __restrict__ src,
                                                       const int* __restrict__ dst,
                                                       const int* __restrict__ countsA,
                                                       const int* __restrict__ bucketBase,
                                                       int* __restrict__ binned, int e)
{
    __shared__ int cur[NBUCK];
    for (int i = threadIdx.x; i < NBUCK; i += 256)
        cur[i] = countsA[blockIdx.x * NBUCK + i] + bucketBase[i];
    __syncthreads();
    int beg = blockIdx.x * EPB, end = min(beg + EPB, e);
    for (int i = beg + threadIdx.x; i < end; i += 256) {
        int d = dst[i], s = src[i];
        int pos = atomicAdd(&cur[d >> 8], 1);          // LDS atomic
        binned[pos] = ((d & 255) << 17) | s;
    }
}

__global__ __launch_bounds__(256) void csr_kernel(const int* __restrict__ binned,
                                                  const int* __restrict__ bucketBase,
                                                  int* __restrict__ srcsorted,
                                                  int* __restrict__ rowptr,
                                                  float* __restrict__ dinv, int n)
{
    __shared__ int hist[256];
    __shared__ int sc[256];
    int b = blockIdx.x, t = threadIdx.x;
    hist[t] = 0;
    __syncthreads();
    int eBeg = bucketBase[b], eEnd = bucketBase[b + 1];
    for (int i = eBeg + t; i < eEnd; i += 256)
        atomicAdd(&hist[binned[i] >> 17], 1);
    __syncthreads();
    int own = hist[t];
    sc[t] = own;
    __syncthreads();
    for (int off = 1; off < 256; off <<= 1) {
        int v = (t >= off) ? sc[t - off] : 0;
        __syncthreads();
        sc[t] += v;
        __syncthreads();
    }
    int excl = sc[t] - own;
    int node = b * 256 + t;
    if (node < n) {
        rowptr[node] = eBeg + excl;
        dinv[node] = 1.0f / sqrtf((float)(own + 1));
    }
    hist[t] = eBeg + excl;
    __syncthreads();
    for (int i = eBeg + t; i < eEnd; i += 256) {
        int v = binned[i];
        int pos = atomicAdd(&hist[v >> 17], 1);
        srcsorted[pos] = v & 0x1FFFF;
    }
}

// ---------------- tiled GEMM + per-row dinv scale (proven) ----------------
template<int KDIM, int NOUT>
__global__ __launch_bounds__(256) void gemm_scale_kernel(
    const float* __restrict__ x, const float* __restrict__ W,
    const float* __restrict__ dinv, float* __restrict__ out, int n)
{
    constexpr int ROWS = 64;
    constexpr int XS = KDIM + 4;
    constexpr int CG = NOUT / 8;
    constexpr int RPT = (ROWS * NOUT) / (256 * 8);
    __shared__ float xs[ROWS * XS];
    __shared__ float Ws[KDIM * NOUT];
    int t = threadIdx.x;
    int row0 = blockIdx.x * ROWS;

    for (int i = t; i < KDIM * NOUT; i += 256) Ws[i] = W[i];
    for (int i = t; i < ROWS * KDIM / 4; i += 256) {
        int r = i / (KDIM / 4);
        int kk = i % (KDIM / 4);
        float4 v = make_float4(0.f, 0.f, 0.f, 0.f);
        if (row0 + r < n) v = ((const float4*)x)[(size_t)(row0 + r) * (KDIM / 4) + kk];
        *(float4*)&xs[r * XS + kk * 4] = v;
    }
    __syncthreads();

    int tcg = t % CG;
    int trow = t / CG;
    float acc[RPT][8];
#pragma unroll
    for (int r = 0; r < RPT; ++r)
#pragma unroll
        for (int j = 0; j < 8; ++j) acc[r][j] = 0.f;

#pragma unroll
    for (int k = 0; k < KDIM; k += 4) {
        float4 xv[RPT];
#pragma unroll
        for (int r = 0; r < RPT; ++r)
            xv[r] = *(float4*)&xs[(trow + r * 32) * XS + k];
#pragma unroll
        for (int kk = 0; kk < 4; ++kk) {
            float4 w0 = *(float4*)&Ws[(k + kk) * NOUT + tcg * 8];
            float4 w1 = *(float4*)&Ws[(k + kk) * NOUT + tcg * 8 + 4];
#pragma unroll
            for (int r = 0; r < RPT; ++r) {
                float xk = ((float*)&xv[r])[kk];
                acc[r][0] += xk * w0.x; acc[r][1] += xk * w0.y;
                acc[r][2] += xk * w0.z; acc[r][3] += xk * w0.w;
                acc[r][4] += xk * w1.x; acc[r][5] += xk * w1.y;
                acc[r][6] += xk * w1.z; acc[r][7] += xk * w1.w;
            }
        }
    }

#pragma unroll
    for (int r = 0; r < RPT; ++r) {
        int row = row0 + trow + r * 32;
        if (row < n) {
            float dv = dinv[row];
            float4 o0 = make_float4(acc[r][0]*dv, acc[r][1]*dv, acc[r][2]*dv, acc[r][3]*dv);
            float4 o1 = make_float4(acc[r][4]*dv, acc[r][5]*dv, acc[r][6]*dv, acc[r][7]*dv);
            *(float4*)&out[(size_t)row * NOUT + tcg * 8]     = o0;
            *(float4*)&out[(size_t)row * NOUT + tcg * 8 + 4] = o1;
        }
    }
}

// ---------------- gather-side aggregation (float4 per thread; proven structure) ----------------
// MODE 0 (layer 1): r = leaky(acc*dinv + bias); store r*dinv  (i.e. s1 = h1*dinv)
// MODE 1 (layer 2): store acc*dinv               (a; W2/b2 applied downstream)
template<int F, int MODE>
__global__ __launch_bounds__(256) void agg_kernel(
    const float* __restrict__ tmp, const int* __restrict__ rowptr,
    const int* __restrict__ srcs, const float* __restrict__ dinv,
    const float* __restrict__ bias, float* __restrict__ out, int n)
{
    constexpr int FG = F / 4;
    int tid = blockIdx.x * blockDim.x + threadIdx.x;
    int node = tid / FG;
    int fg = tid % FG;
    if (node >= n) return;
    int beg = rowptr[node], end = rowptr[node + 1];
    const float4* t4 = (const float4*)tmp;
    float4 acc = t4[(size_t)node * FG + fg];   // self-loop
    int j = beg;
    for (; j + 4 <= end; j += 4) {
        int s0 = srcs[j], s1 = srcs[j + 1], s2 = srcs[j + 2], s3 = srcs[j + 3];
        float4 v0 = t4[(size_t)s0 * FG + fg];
        float4 v1 = t4[(size_t)s1 * FG + fg];
        float4 v2 = t4[(size_t)s2 * FG + fg];
        float4 v3 = t4[(size_t)s3 * FG + fg];
        acc.x += v0.x; acc.y += v0.y; acc.z += v0.z; acc.w += v0.w;
        acc.x += v1.x; acc.y += v1.y; acc.z += v1.z; acc.w += v1.w;
        acc.x += v2.x; acc.y += v2.y; acc.z += v2.z; acc.w += v2.w;
        acc.x += v3.x; acc.y += v3.y; acc.z += v3.z; acc.w += v3.w;
    }
    for (; j < end; ++j) {
        float4 v = t4[(size_t)srcs[j] * FG + fg];
        acc.x += v.x; acc.y += v.y; acc.z += v.z; acc.w += v.w;
    }
    float dv = dinv[node];
    float4 r;
    if (MODE == 0) {
        float4 bb = ((const float4*)bias)[fg];
        r.x = acc.x * dv + bb.x; r.y = acc.y * dv + bb.y;
        r.z = acc.z * dv + bb.z; r.w = acc.w * dv + bb.w;
        r.x = (r.x > 0.f) ? r.x : 0.1f * r.x;
        r.y = (r.y > 0.f) ? r.y : 0.1f * r.y;
        r.z = (r.z > 0.f) ? r.z : 0.1f * r.z;
        r.w = (r.w > 0.f) ? r.w : 0.1f * r.w;
        r.x *= dv; r.y *= dv; r.z *= dv; r.w *= dv;
    } else {
        r.x = acc.x * dv; r.y = acc.y * dv; r.z = acc.z * dv; r.w = acc.w * dv;
    }
    ((float4*)out)[(size_t)node * FG + fg] = r;
}

// ---------------- fused gemm(32->64)+bias+segmax per graph ----------------
// h2[i] = a[i] @ W2 + b2 never materialized; 256 blocks (one per graph),
// 256 threads = 4 nodes x 64 features. W2 column held in registers.
__global__ __launch_bounds__(256) void gemmsegmax_kernel(
    const float* __restrict__ a, const float* __restrict__ W2,
    const float* __restrict__ b2, float* __restrict__ g, int n)
{
    __shared__ float Ws[H1DIM * H2DIM];   // 8 KB
    __shared__ float rows[4 * H1DIM];     // 4 node rows, contiguous
    __shared__ float red[256];
    int t = threadIdx.x, gr = blockIdx.x;
    for (int i = t; i < H1DIM * H2DIM; i += 256) Ws[i] = W2[i];
    __syncthreads();
    int sub = t >> 6, f = t & 63;
    float wreg[H1DIM];
#pragma unroll
    for (int k = 0; k < H1DIM; ++k) wreg[k] = Ws[k * H2DIM + f];
    float bf = b2[f];
    int start = (gr * n + NGRAPH - 1) / NGRAPH;
    int end = ((gr + 1) * n + NGRAPH - 1) / NGRAPH;
    float m = -INFINITY;
    for (int i0 = start; i0 < end; i0 += 4) {
        __syncthreads();
        if (t < 128) {
            int idx = i0 * H1DIM + t;
            rows[t] = (idx < n * H1DIM) ? a[idx] : 0.f;
        }
        __syncthreads();
        int i = i0 + sub;
        if (i < end) {
            float acc = bf;
#pragma unroll
            for (int k = 0; k < H1DIM; k += 4) {
                float4 rv = *(float4*)&rows[sub * H1DIM + k];   // broadcast b128
                acc += rv.x * wreg[k] + rv.y * wreg[k + 1]
                     + rv.z * wreg[k + 2] + rv.w * wreg[k + 3];
            }
            m = fmaxf(m, acc);
        }
    }
    red[t] = m;
    __syncthreads();
    if (t < 64) {
        float v = fmaxf(fmaxf(red[t], red[t + 64]), fmaxf(red[t + 128], red[t + 192]));
        g[gr * H2DIM + t] = v;
    }
}

// ---------------- tiny MLP head ----------------
__global__ __launch_bounds__(128) void mlp_kernel(
    const float* __restrict__ g,
    const float* __restrict__ l1W, const float* __restrict__ l1b,
    const float* __restrict__ l2W, const float* __restrict__ l2b,
    const float* __restrict__ l3W, const float* __restrict__ l3b,
    float* __restrict__ out)
{
    __shared__ float gin[64], z1[128], z2[64];
    int b = blockIdx.x, t = threadIdx.x;
    if (t < 64) gin[t] = g[b * 64 + t];
    __syncthreads();
    {
        float a = l1b[t];
        for (int k = 0; k < 64; ++k) a += gin[k] * l1W[k * 128 + t];
        z1[t] = (a > 0.f) ? a : 0.1f * a;
    }
    __syncthreads();
    if (t < 64) {
        float a = l2b[t];
        for (int k = 0; k < 128; ++k) a += z1[k] * l2W[k * 64 + t];
        z2[t] = (a > 0.f) ? a : 0.1f * a;
    }
    __syncthreads();
    if (t < 64) {
        float a = l3b[t];
        for (int k = 0; k < 64; ++k) a += z2[k] * l3W[k * 64 + t];
        out[b * 64 + t] = a;
    }
}

extern "C" void kernel_launch(void* const* d_in, const int* in_sizes, int n_in,
                              void* d_out, int out_size, void* d_ws, size_t ws_size,
                              hipStream_t stream) {
    const float* x   = (const float*)d_in[0];
    const int*   ei  = (const int*)d_in[1];
    const int*   src = ei;
    const int*   dst = ei + N_EDGES;
    const float* W1  = (const float*)d_in[3];
    const float* b1  = (const float*)d_in[4];
    const float* W2  = (const float*)d_in[5];
    const float* b2  = (const float*)d_in[6];
    const float* l1W = (const float*)d_in[7];
    const float* l1b = (const float*)d_in[8];
    const float* l2W = (const float*)d_in[9];
    const float* l2b = (const float*)d_in[10];
    const float* l3W = (const float*)d_in[11];
    const float* l3b = (const float*)d_in[12];
    float* outp = (float*)d_out;

    char* w = (char*)d_ws;
    size_t off = 0;
    auto alloc = [&](size_t bytes) { char* p = w + off; off += (bytes + 255) & ~(size_t)255; return p; };
    int*   countsA    = (int*)  alloc((size_t)NBLK_A * NBUCK * sizeof(int));
    int*   bucketBase = (int*)  alloc((NBUCK + 1) * sizeof(int));
    int*   rowptr     = (int*)  alloc((N_NODES + 1) * sizeof(int));
    float* dinv       = (float*)alloc(N_NODES * sizeof(float));
    int*   srcsorted  = (int*)  alloc(N_EDGES * sizeof(int));
    float* bufA       = (float*)alloc((size_t)N_NODES * 64 * sizeof(float));
    float* bufB       = (float*)alloc((size_t)N_NODES * 32 * sizeof(float));
    float* gbuf       = (float*)alloc(NGRAPH * H2DIM * sizeof(float));

    float* tmp1 = bufA;  // [N,32] lower half of bufA
    float* s1   = bufB;  // [N,32] = h1*dinv
    float* abuf = bufA;  // [N,32] overlay (tmp1 dead after agg1)
    // binned (E ints = 12.8 MB) overlays upper half of bufA: dead after csr_kernel.
    int* binned = (int*)(bufA + (size_t)N_NODES * 32);

    binhist_kernel<<<NBLK_A, 256, 0, stream>>>(dst, countsA, N_EDGES);
    scanA_kernel<<<1, 512, 0, stream>>>(countsA, bucketBase, rowptr);
    binplace_kernel<<<NBLK_A, 256, 0, stream>>>(src, dst, countsA, bucketBase, binned, N_EDGES);
    csr_kernel<<<NBUCK, 256, 0, stream>>>(binned, bucketBase, srcsorted, rowptr, dinv, N_NODES);

    gemm_scale_kernel<F_INPUT, H1DIM><<<(N_NODES + 63) / 64, 256, 0, stream>>>(x, W1, dinv, tmp1, N_NODES);
    agg_kernel<H1DIM, 0><<<((size_t)N_NODES * (H1DIM/4) + 255) / 256, 256, 0, stream>>>(
        tmp1, rowptr, srcsorted, dinv, b1, s1, N_NODES);
    agg_kernel<H1DIM, 1><<<((size_t)N_NODES * (H1DIM/4) + 255) / 256, 256, 0, stream>>>(
        s1, rowptr, srcsorted, dinv, b1 /*unused*/, abuf, N_NODES);

    gemmsegmax_kernel<<<NGRAPH, 256, 0, stream>>>(abuf, W2, b2, gbuf, N_NODES);
    mlp_kernel<<<NGRAPH, 128, 0, stream>>>(gbuf, l1W, l1b, l2W, l2b, l3W, l3b, outp);
}

// Round 7
// 357.060 us; speedup vs baseline: 3.0844x; 1.1261x over previous
//
#include <hip/hip_runtime.h>
#include <math.h>

#define N_NODES 100000
#define N_EDGES 3200000
#define F_INPUT 128
#define H1DIM 32
#define H2DIM 64
#define NGRAPH 256
#define NACT 64
#define EPB 16384                          // edges per binning block
#define NBLK_A ((N_EDGES + EPB - 1) / EPB) // 196
#define NBUCK ((N_NODES + 255) / 256)      // 391 buckets of 256 dst nodes

// ---------------- CSR build: LDS-staged two-level binning (proven R5) ----------------
__global__ __launch_bounds__(256) void binhist_kernel(const int* __restrict__ dst,
                                                      int* __restrict__ countsA, int e)
{
    __shared__ int hist[NBUCK];
    for (int i = threadIdx.x; i < NBUCK; i += 256) hist[i] = 0;
    __syncthreads();
    int beg = blockIdx.x * EPB, end = min(beg + EPB, e);
    for (int i = beg + threadIdx.x; i < end; i += 256)
        atomicAdd(&hist[dst[i] >> 8], 1);
    __syncthreads();
    for (int i = threadIdx.x; i < NBUCK; i += 256)
        countsA[blockIdx.x * NBUCK + i] = hist[i];   // coalesced
}

__global__ __launch_bounds__(512) void scanA_kernel(int* __restrict__ countsA,
                                                    int* __restrict__ bucketBase,
                                                    int* __restrict__ rowptr)
{
    __shared__ int sums[512];
    int b = threadIdx.x;
    int run = 0;
    if (b < NBUCK) {
        for (int blk = 0; blk < NBLK_A; ++blk) {
            int t = countsA[blk * NBUCK + b];
            countsA[blk * NBUCK + b] = run;
            run += t;
        }
    }
    int own = (b < NBUCK) ? run : 0;
    sums[b] = own;
    __syncthreads();
    for (int off = 1; off < 512; off <<= 1) {
        int v = (b >= off) ? sums[b - off] : 0;
        __syncthreads();
        sums[b] += v;
        __syncthreads();
    }
    if (b < NBUCK) bucketBase[b] = sums[b] - own;
    if (b == 0) { bucketBase[NBUCK] = N_EDGES; rowptr[N_NODES] = N_EDGES; }
}

__global__ __launch_bounds__(256) void binplace_kernel(const int* __restrict__ src,
                                                       const int* __restrict__ dst,
                                                       const int* __restrict__ countsA,
                                                       const int* __restrict__ bucketBase,
                                                       int* __restrict__ binned, int e)
{
    __shared__ int cur[NBUCK];
    for (int i = threadIdx.x; i < NBUCK; i += 256)
        cur[i] = countsA[blockIdx.x * NBUCK + i] + bucketBase[i];
    __syncthreads();
    int beg = blockIdx.x * EPB, end = min(beg + EPB, e);
    for (int i = beg + threadIdx.x; i < end; i += 256) {
        int d = dst[i], s = src[i];
        int pos = atomicAdd(&cur[d >> 8], 1);          // LDS atomic
        binned[pos] = ((d & 255) << 17) | s;
    }
}

__global__ __launch_bounds__(256) void csr_kernel(const int* __restrict__ binned,
                                                  const int* __restrict__ bucketBase,
                                                  int* __restrict__ srcsorted,
                                                  int* __restrict__ rowptr,
                                                  float* __restrict__ dinv, int n)
{
    __shared__ int hist[256];
    __shared__ int sc[256];
    int b = blockIdx.x, t = threadIdx.x;
    hist[t] = 0;
    __syncthreads();
    int eBeg = bucketBase[b], eEnd = bucketBase[b + 1];
    for (int i = eBeg + t; i < eEnd; i += 256)
        atomicAdd(&hist[binned[i] >> 17], 1);
    __syncthreads();
    int own = hist[t];
    sc[t] = own;
    __syncthreads();
    for (int off = 1; off < 256; off <<= 1) {
        int v = (t >= off) ? sc[t - off] : 0;
        __syncthreads();
        sc[t] += v;
        __syncthreads();
    }
    int excl = sc[t] - own;
    int node = b * 256 + t;
    if (node < n) {
        rowptr[node] = eBeg + excl;
        dinv[node] = 1.0f / sqrtf((float)(own + 1));
    }
    hist[t] = eBeg + excl;
    __syncthreads();
    for (int i = eBeg + t; i < eEnd; i += 256) {
        int v = binned[i];
        int pos = atomicAdd(&hist[v >> 17], 1);
        srcsorted[pos] = v & 0x1FFFF;
    }
}

// ---------------- tiled GEMM + per-row dinv scale (proven) ----------------
template<int KDIM, int NOUT>
__global__ __launch_bounds__(256) void gemm_scale_kernel(
    const float* __restrict__ x, const float* __restrict__ W,
    const float* __restrict__ dinv, float* __restrict__ out, int n)
{
    constexpr int ROWS = 64;
    constexpr int XS = KDIM + 4;
    constexpr int CG = NOUT / 8;
    constexpr int RPT = (ROWS * NOUT) / (256 * 8);
    __shared__ float xs[ROWS * XS];
    __shared__ float Ws[KDIM * NOUT];
    int t = threadIdx.x;
    int row0 = blockIdx.x * ROWS;

    for (int i = t; i < KDIM * NOUT; i += 256) Ws[i] = W[i];
    for (int i = t; i < ROWS * KDIM / 4; i += 256) {
        int r = i / (KDIM / 4);
        int kk = i % (KDIM / 4);
        float4 v = make_float4(0.f, 0.f, 0.f, 0.f);
        if (row0 + r < n) v = ((const float4*)x)[(size_t)(row0 + r) * (KDIM / 4) + kk];
        *(float4*)&xs[r * XS + kk * 4] = v;
    }
    __syncthreads();

    int tcg = t % CG;
    int trow = t / CG;
    float acc[RPT][8];
#pragma unroll
    for (int r = 0; r < RPT; ++r)
#pragma unroll
        for (int j = 0; j < 8; ++j) acc[r][j] = 0.f;

#pragma unroll
    for (int k = 0; k < KDIM; k += 4) {
        float4 xv[RPT];
#pragma unroll
        for (int r = 0; r < RPT; ++r)
            xv[r] = *(float4*)&xs[(trow + r * 32) * XS + k];
#pragma unroll
        for (int kk = 0; kk < 4; ++kk) {
            float4 w0 = *(float4*)&Ws[(k + kk) * NOUT + tcg * 8];
            float4 w1 = *(float4*)&Ws[(k + kk) * NOUT + tcg * 8 + 4];
#pragma unroll
            for (int r = 0; r < RPT; ++r) {
                float xk = ((float*)&xv[r])[kk];
                acc[r][0] += xk * w0.x; acc[r][1] += xk * w0.y;
                acc[r][2] += xk * w0.z; acc[r][3] += xk * w0.w;
                acc[r][4] += xk * w1.x; acc[r][5] += xk * w1.y;
                acc[r][6] += xk * w1.z; acc[r][7] += xk * w1.w;
            }
        }
    }

#pragma unroll
    for (int r = 0; r < RPT; ++r) {
        int row = row0 + trow + r * 32;
        if (row < n) {
            float dv = dinv[row];
            float4 o0 = make_float4(acc[r][0]*dv, acc[r][1]*dv, acc[r][2]*dv, acc[r][3]*dv);
            float4 o1 = make_float4(acc[r][4]*dv, acc[r][5]*dv, acc[r][6]*dv, acc[r][7]*dv);
            *(float4*)&out[(size_t)row * NOUT + tcg * 8]     = o0;
            *(float4*)&out[(size_t)row * NOUT + tcg * 8 + 4] = o1;
        }
    }
}

// ---------------- gather-side aggregation (float4 per thread; proven) ----------------
// MODE 0 (layer 1): r = leaky(acc*dinv + bias); store r*dinv  (i.e. s1 = h1*dinv)
// MODE 1 (layer 2): store acc*dinv               (a; W2/b2 applied downstream)
template<int F, int MODE>
__global__ __launch_bounds__(256) void agg_kernel(
    const float* __restrict__ tmp, const int* __restrict__ rowptr,
    const int* __restrict__ srcs, const float* __restrict__ dinv,
    const float* __restrict__ bias, float* __restrict__ out, int n)
{
    constexpr int FG = F / 4;
    int tid = blockIdx.x * blockDim.x + threadIdx.x;
    int node = tid / FG;
    int fg = tid % FG;
    if (node >= n) return;
    int beg = rowptr[node], end = rowptr[node + 1];
    const float4* t4 = (const float4*)tmp;
    float4 acc = t4[(size_t)node * FG + fg];   // self-loop
    int j = beg;
    for (; j + 4 <= end; j += 4) {
        int s0 = srcs[j], s1 = srcs[j + 1], s2 = srcs[j + 2], s3 = srcs[j + 3];
        float4 v0 = t4[(size_t)s0 * FG + fg];
        float4 v1 = t4[(size_t)s1 * FG + fg];
        float4 v2 = t4[(size_t)s2 * FG + fg];
        float4 v3 = t4[(size_t)s3 * FG + fg];
        acc.x += v0.x; acc.y += v0.y; acc.z += v0.z; acc.w += v0.w;
        acc.x += v1.x; acc.y += v1.y; acc.z += v1.z; acc.w += v1.w;
        acc.x += v2.x; acc.y += v2.y; acc.z += v2.z; acc.w += v2.w;
        acc.x += v3.x; acc.y += v3.y; acc.z += v3.z; acc.w += v3.w;
    }
    for (; j < end; ++j) {
        float4 v = t4[(size_t)srcs[j] * FG + fg];
        acc.x += v.x; acc.y += v.y; acc.z += v.z; acc.w += v.w;
    }
    float dv = dinv[node];
    float4 r;
    if (MODE == 0) {
        float4 bb = ((const float4*)bias)[fg];
        r.x = acc.x * dv + bb.x; r.y = acc.y * dv + bb.y;
        r.z = acc.z * dv + bb.z; r.w = acc.w * dv + bb.w;
        r.x = (r.x > 0.f) ? r.x : 0.1f * r.x;
        r.y = (r.y > 0.f) ? r.y : 0.1f * r.y;
        r.z = (r.z > 0.f) ? r.z : 0.1f * r.z;
        r.w = (r.w > 0.f) ? r.w : 0.1f * r.w;
        r.x *= dv; r.y *= dv; r.z *= dv; r.w *= dv;
    } else {
        r.x = acc.x * dv; r.y = acc.y * dv; r.z = acc.z * dv; r.w = acc.w * dv;
    }
    ((float4*)out)[(size_t)node * FG + fg] = r;
}

// ---------------- init gbuf to -inf ----------------
__global__ void initg_kernel(float* __restrict__ g)
{
    int i = blockIdx.x * blockDim.x + threadIdx.x;
    if (i < NGRAPH * H2DIM) g[i] = -INFINITY;
}

__device__ inline void atomicMaxFloat(float* addr, float val)
{
    if (val >= 0.f) atomicMax((int*)addr, __float_as_int(val));
    else            atomicMin((unsigned int*)addr, __float_as_uint(val));
}

// ---------------- node-parallel fused gemm(32->64)+bias+segmax ----------------
// 1563 blocks x 64 nodes. Rows staged in LDS once (single barrier pair).
// A 64-node window spans <=2 graphs (min graph size ~390); block-local max
// per (graph,feature) then device atomicMax into gbuf (init'd to -inf).
__global__ __launch_bounds__(256) void gemmsegmax_kernel(
    const float* __restrict__ a, const float* __restrict__ W2,
    const float* __restrict__ b2, float* __restrict__ g, int n)
{
    __shared__ float Ws[H1DIM * H2DIM];     // 8 KB
    __shared__ float rows[64 * H1DIM];      // 8 KB
    __shared__ float redA[256], redB[256];
    int t = threadIdx.x;
    int base = blockIdx.x * 64;
    int lim = min(base + 64, n);
    for (int i = t; i < H1DIM * H2DIM; i += 256) Ws[i] = W2[i];
    {
        const float4* a4 = (const float4*)a;
        int nf4 = (lim - base) * (H1DIM / 4);             // <= 512 float4s
        for (int i = t; i < nf4; i += 256)
            ((float4*)rows)[i] = a4[(size_t)base * (H1DIM / 4) + i];
    }
    __syncthreads();
    int sub = t >> 6, f = t & 63;
    float wreg[H1DIM];
#pragma unroll
    for (int k = 0; k < H1DIM; ++k) wreg[k] = Ws[k * H2DIM + f];
    float bf = b2[f];
    int gidA = (int)(((long long)base * NGRAPH) / n);     // == batch[base]
    float mA = -INFINITY, mB = -INFINITY;
    for (int i = base + sub; i < lim; i += 4) {
        float acc = bf;
        int lr = i - base;
#pragma unroll
        for (int k = 0; k < H1DIM; k += 4) {
            float4 rv = *(float4*)&rows[lr * H1DIM + k];
            acc += rv.x * wreg[k] + rv.y * wreg[k + 1]
                 + rv.z * wreg[k + 2] + rv.w * wreg[k + 3];
        }
        int gid = (int)(((long long)i * NGRAPH) / n);
        if (gid == gidA) mA = fmaxf(mA, acc);
        else             mB = fmaxf(mB, acc);
    }
    redA[t] = mA; redB[t] = mB;
    __syncthreads();
    if (t < 64) {
        float v = fmaxf(fmaxf(redA[t], redA[t + 64]), fmaxf(redA[t + 128], redA[t + 192]));
        if (v > -INFINITY) atomicMaxFloat(&g[gidA * H2DIM + t], v);
    } else if (t < 128) {
        int f2 = t - 64;
        float v = fmaxf(fmaxf(redB[f2], redB[f2 + 64]), fmaxf(redB[f2 + 128], redB[f2 + 192]));
        int gidB = gidA + 1;
        if (gidB < NGRAPH && v > -INFINITY) atomicMaxFloat(&g[gidB * H2DIM + f2], v);
    }
}

// ---------------- tiny MLP head ----------------
__global__ __launch_bounds__(128) void mlp_kernel(
    const float* __restrict__ g,
    const float* __restrict__ l1W, const float* __restrict__ l1b,
    const float* __restrict__ l2W, const float* __restrict__ l2b,
    const float* __restrict__ l3W, const float* __restrict__ l3b,
    float* __restrict__ out)
{
    __shared__ float gin[64], z1[128], z2[64];
    int b = blockIdx.x, t = threadIdx.x;
    if (t < 64) gin[t] = g[b * 64 + t];
    __syncthreads();
    {
        float a = l1b[t];
        for (int k = 0; k < 64; ++k) a += gin[k] * l1W[k * 128 + t];
        z1[t] = (a > 0.f) ? a : 0.1f * a;
    }
    __syncthreads();
    if (t < 64) {
        float a = l2b[t];
        for (int k = 0; k < 128; ++k) a += z1[k] * l2W[k * 64 + t];
        z2[t] = (a > 0.f) ? a : 0.1f * a;
    }
    __syncthreads();
    if (t < 64) {
        float a = l3b[t];
        for (int k = 0; k < 64; ++k) a += z2[k] * l3W[k * 64 + t];
        out[b * 64 + t] = a;
    }
}

extern "C" void kernel_launch(void* const* d_in, const int* in_sizes, int n_in,
                              void* d_out, int out_size, void* d_ws, size_t ws_size,
                              hipStream_t stream) {
    const float* x   = (const float*)d_in[0];
    const int*   ei  = (const int*)d_in[1];
    const int*   src = ei;
    const int*   dst = ei + N_EDGES;
    const float* W1  = (const float*)d_in[3];
    const float* b1  = (const float*)d_in[4];
    const float* W2  = (const float*)d_in[5];
    const float* b2  = (const float*)d_in[6];
    const float* l1W = (const float*)d_in[7];
    const float* l1b = (const float*)d_in[8];
    const float* l2W = (const float*)d_in[9];
    const float* l2b = (const float*)d_in[10];
    const float* l3W = (const float*)d_in[11];
    const float* l3b = (const float*)d_in[12];
    float* outp = (float*)d_out;

    char* w = (char*)d_ws;
    size_t off = 0;
    auto alloc = [&](size_t bytes) { char* p = w + off; off += (bytes + 255) & ~(size_t)255; return p; };
    int*   countsA    = (int*)  alloc((size_t)NBLK_A * NBUCK * sizeof(int));
    int*   bucketBase = (int*)  alloc((NBUCK + 1) * sizeof(int));
    int*   rowptr     = (int*)  alloc((N_NODES + 1) * sizeof(int));
    float* dinv       = (float*)alloc(N_NODES * sizeof(float));
    int*   srcsorted  = (int*)  alloc(N_EDGES * sizeof(int));
    float* bufA       = (float*)alloc((size_t)N_NODES * 64 * sizeof(float));
    float* bufB       = (float*)alloc((size_t)N_NODES * 32 * sizeof(float));
    float* gbuf       = (float*)alloc(NGRAPH * H2DIM * sizeof(float));

    float* tmp1 = bufA;  // [N,32] lower half of bufA
    float* s1   = bufB;  // [N,32] = h1*dinv
    float* abuf = bufA;  // [N,32] overlay (tmp1 dead after agg1)
    // binned (E ints = 12.8 MB) overlays upper half of bufA: dead after csr_kernel.
    int* binned = (int*)(bufA + (size_t)N_NODES * 32);

    binhist_kernel<<<NBLK_A, 256, 0, stream>>>(dst, countsA, N_EDGES);
    scanA_kernel<<<1, 512, 0, stream>>>(countsA, bucketBase, rowptr);
    binplace_kernel<<<NBLK_A, 256, 0, stream>>>(src, dst, countsA, bucketBase, binned, N_EDGES);
    csr_kernel<<<NBUCK, 256, 0, stream>>>(binned, bucketBase, srcsorted, rowptr, dinv, N_NODES);

    gemm_scale_kernel<F_INPUT, H1DIM><<<(N_NODES + 63) / 64, 256, 0, stream>>>(x, W1, dinv, tmp1, N_NODES);
    agg_kernel<H1DIM, 0><<<((size_t)N_NODES * (H1DIM/4) + 255) / 256, 256, 0, stream>>>(
        tmp1, rowptr, srcsorted, dinv, b1, s1, N_NODES);
    initg_kernel<<<(NGRAPH * H2DIM + 255) / 256, 256, 0, stream>>>(gbuf);
    agg_kernel<H1DIM, 1><<<((size_t)N_NODES * (H1DIM/4) + 255) / 256, 256, 0, stream>>>(
        s1, rowptr, srcsorted, dinv, b1 /*unused*/, abuf, N_NODES);

    gemmsegmax_kernel<<<(N_NODES + 63) / 64, 256, 0, stream>>>(abuf, W2, b2, gbuf, N_NODES);
    mlp_kernel<<<NGRAPH, 128, 0, stream>>>(gbuf, l1W, l1b, l2W, l2b, l3W, l3b, outp);
}

// Round 8
// 350.633 us; speedup vs baseline: 3.1409x; 1.0183x over previous
//
#include <hip/hip_runtime.h>
#include <math.h>

#define N_NODES 100000
#define N_EDGES 3200000
#define F_INPUT 128
#define H1DIM 32
#define H2DIM 64
#define NGRAPH 256
#define NACT 64
#define EPB 16384                          // edges per binning block
#define NBLK_A ((N_EDGES + EPB - 1) / EPB) // 196
#define NBUCK ((N_NODES + 255) / 256)      // 391 buckets of 256 dst nodes

// ---------------- CSR build: LDS-staged two-level binning (proven R5) ----------------
__global__ __launch_bounds__(256) void binhist_kernel(const int* __restrict__ dst,
                                                      int* __restrict__ countsA, int e)
{
    __shared__ int hist[NBUCK];
    for (int i = threadIdx.x; i < NBUCK; i += 256) hist[i] = 0;
    __syncthreads();
    int beg = blockIdx.x * EPB, end = min(beg + EPB, e);
    for (int i = beg + threadIdx.x; i < end; i += 256)
        atomicAdd(&hist[dst[i] >> 8], 1);
    __syncthreads();
    for (int i = threadIdx.x; i < NBUCK; i += 256)
        countsA[blockIdx.x * NBUCK + i] = hist[i];   // coalesced
}

// Parallel within-bucket scan: one wave per bucket, shuffle prefix over 196
// per-block counts. Replaces the single-workgroup serial scanA.
__global__ __launch_bounds__(64) void scanAp_kernel(int* __restrict__ countsA,
                                                    int* __restrict__ bucketTot)
{
    int b = blockIdx.x;            // bucket
    int lane = threadIdx.x;        // 0..63
    int carry = 0;
    for (int r = 0; r < (NBLK_A + 63) / 64; ++r) {
        int blk = r * 64 + lane;
        int v = (blk < NBLK_A) ? countsA[blk * NBUCK + b] : 0;
        int own = v;
        for (int d = 1; d < 64; d <<= 1) {
            int t = __shfl_up(v, d);
            if (lane >= d) v += t;
        }
        if (blk < NBLK_A) countsA[blk * NBUCK + b] = v - own + carry;
        carry += __shfl(v, 63);    // round total
    }
    if (lane == 0) bucketTot[b] = carry;
}

// Top-level exclusive scan over 391 bucket totals.
__global__ __launch_bounds__(512) void scanB_kernel(const int* __restrict__ bucketTot,
                                                    int* __restrict__ bucketBase,
                                                    int* __restrict__ rowptr)
{
    __shared__ int sums[512];
    int b = threadIdx.x;
    int own = (b < NBUCK) ? bucketTot[b] : 0;
    sums[b] = own;
    __syncthreads();
    for (int off = 1; off < 512; off <<= 1) {
        int v = (b >= off) ? sums[b - off] : 0;
        __syncthreads();
        sums[b] += v;
        __syncthreads();
    }
    if (b < NBUCK) bucketBase[b] = sums[b] - own;
    if (b == 0) { bucketBase[NBUCK] = N_EDGES; rowptr[N_NODES] = N_EDGES; }
}

__global__ __launch_bounds__(256) void binplace_kernel(const int* __restrict__ src,
                                                       const int* __restrict__ dst,
                                                       const int* __restrict__ countsA,
                                                       const int* __restrict__ bucketBase,
                                                       int* __restrict__ binned, int e)
{
    __shared__ int cur[NBUCK];
    for (int i = threadIdx.x; i < NBUCK; i += 256)
        cur[i] = countsA[blockIdx.x * NBUCK + i] + bucketBase[i];
    __syncthreads();
    int beg = blockIdx.x * EPB, end = min(beg + EPB, e);
    for (int i = beg + threadIdx.x; i < end; i += 256) {
        int d = dst[i], s = src[i];
        int pos = atomicAdd(&cur[d >> 8], 1);          // LDS atomic
        binned[pos] = ((d & 255) << 17) | s;
    }
}

__global__ __launch_bounds__(256) void csr_kernel(const int* __restrict__ binned,
                                                  const int* __restrict__ bucketBase,
                                                  int* __restrict__ srcsorted,
                                                  int* __restrict__ rowptr,
                                                  float* __restrict__ dinv, int n)
{
    __shared__ int hist[256];
    __shared__ int sc[256];
    int b = blockIdx.x, t = threadIdx.x;
    hist[t] = 0;
    __syncthreads();
    int eBeg = bucketBase[b], eEnd = bucketBase[b + 1];
    for (int i = eBeg + t; i < eEnd; i += 256)
        atomicAdd(&hist[binned[i] >> 17], 1);
    __syncthreads();
    int own = hist[t];
    sc[t] = own;
    __syncthreads();
    for (int off = 1; off < 256; off <<= 1) {
        int v = (t >= off) ? sc[t - off] : 0;
        __syncthreads();
        sc[t] += v;
        __syncthreads();
    }
    int excl = sc[t] - own;
    int node = b * 256 + t;
    if (node < n) {
        rowptr[node] = eBeg + excl;
        dinv[node] = 1.0f / sqrtf((float)(own + 1));
    }
    hist[t] = eBeg + excl;
    __syncthreads();
    for (int i = eBeg + t; i < eEnd; i += 256) {
        int v = binned[i];
        int pos = atomicAdd(&hist[v >> 17], 1);
        srcsorted[pos] = v & 0x1FFFF;
    }
}

// ---------------- tiled GEMM + per-row dinv scale (proven) ----------------
template<int KDIM, int NOUT>
__global__ __launch_bounds__(256) void gemm_scale_kernel(
    const float* __restrict__ x, const float* __restrict__ W,
    const float* __restrict__ dinv, float* __restrict__ out, int n)
{
    constexpr int ROWS = 64;
    constexpr int XS = KDIM + 4;
    constexpr int CG = NOUT / 8;
    constexpr int RPT = (ROWS * NOUT) / (256 * 8);
    __shared__ float xs[ROWS * XS];
    __shared__ float Ws[KDIM * NOUT];
    int t = threadIdx.x;
    int row0 = blockIdx.x * ROWS;

    for (int i = t; i < KDIM * NOUT; i += 256) Ws[i] = W[i];
    for (int i = t; i < ROWS * KDIM / 4; i += 256) {
        int r = i / (KDIM / 4);
        int kk = i % (KDIM / 4);
        float4 v = make_float4(0.f, 0.f, 0.f, 0.f);
        if (row0 + r < n) v = ((const float4*)x)[(size_t)(row0 + r) * (KDIM / 4) + kk];
        *(float4*)&xs[r * XS + kk * 4] = v;
    }
    __syncthreads();

    int tcg = t % CG;
    int trow = t / CG;
    float acc[RPT][8];
#pragma unroll
    for (int r = 0; r < RPT; ++r)
#pragma unroll
        for (int j = 0; j < 8; ++j) acc[r][j] = 0.f;

#pragma unroll
    for (int k = 0; k < KDIM; k += 4) {
        float4 xv[RPT];
#pragma unroll
        for (int r = 0; r < RPT; ++r)
            xv[r] = *(float4*)&xs[(trow + r * 32) * XS + k];
#pragma unroll
        for (int kk = 0; kk < 4; ++kk) {
            float4 w0 = *(float4*)&Ws[(k + kk) * NOUT + tcg * 8];
            float4 w1 = *(float4*)&Ws[(k + kk) * NOUT + tcg * 8 + 4];
#pragma unroll
            for (int r = 0; r < RPT; ++r) {
                float xk = ((float*)&xv[r])[kk];
                acc[r][0] += xk * w0.x; acc[r][1] += xk * w0.y;
                acc[r][2] += xk * w0.z; acc[r][3] += xk * w0.w;
                acc[r][4] += xk * w1.x; acc[r][5] += xk * w1.y;
                acc[r][6] += xk * w1.z; acc[r][7] += xk * w1.w;
            }
        }
    }

#pragma unroll
    for (int r = 0; r < RPT; ++r) {
        int row = row0 + trow + r * 32;
        if (row < n) {
            float dv = dinv[row];
            float4 o0 = make_float4(acc[r][0]*dv, acc[r][1]*dv, acc[r][2]*dv, acc[r][3]*dv);
            float4 o1 = make_float4(acc[r][4]*dv, acc[r][5]*dv, acc[r][6]*dv, acc[r][7]*dv);
            *(float4*)&out[(size_t)row * NOUT + tcg * 8]     = o0;
            *(float4*)&out[(size_t)row * NOUT + tcg * 8 + 4] = o1;
        }
    }
}

// ---------------- gather-side aggregation (float4/thread, 8-deep ILP) ----------------
// MODE 0 (layer 1): r = leaky(acc*dinv + bias); store r*dinv  (i.e. s1 = h1*dinv)
// MODE 1 (layer 2): store acc*dinv               (a; W2/b2 applied downstream)
template<int F, int MODE>
__global__ __launch_bounds__(256) void agg_kernel(
    const float* __restrict__ tmp, const int* __restrict__ rowptr,
    const int* __restrict__ srcs, const float* __restrict__ dinv,
    const float* __restrict__ bias, float* __restrict__ out, int n)
{
    constexpr int FG = F / 4;
    int tid = blockIdx.x * blockDim.x + threadIdx.x;
    int node = tid / FG;
    int fg = tid % FG;
    if (node >= n) return;
    int beg = rowptr[node], end = rowptr[node + 1];
    const float4* t4 = (const float4*)tmp;
    float4 acc = t4[(size_t)node * FG + fg];   // self-loop
    int j = beg;
    for (; j + 8 <= end; j += 8) {
        int s0 = srcs[j],     s1 = srcs[j + 1], s2 = srcs[j + 2], s3 = srcs[j + 3];
        int s4 = srcs[j + 4], s5 = srcs[j + 5], s6 = srcs[j + 6], s7 = srcs[j + 7];
        float4 v0 = t4[(size_t)s0 * FG + fg];
        float4 v1 = t4[(size_t)s1 * FG + fg];
        float4 v2 = t4[(size_t)s2 * FG + fg];
        float4 v3 = t4[(size_t)s3 * FG + fg];
        float4 v4 = t4[(size_t)s4 * FG + fg];
        float4 v5 = t4[(size_t)s5 * FG + fg];
        float4 v6 = t4[(size_t)s6 * FG + fg];
        float4 v7 = t4[(size_t)s7 * FG + fg];
        acc.x += v0.x; acc.y += v0.y; acc.z += v0.z; acc.w += v0.w;
        acc.x += v1.x; acc.y += v1.y; acc.z += v1.z; acc.w += v1.w;
        acc.x += v2.x; acc.y += v2.y; acc.z += v2.z; acc.w += v2.w;
        acc.x += v3.x; acc.y += v3.y; acc.z += v3.z; acc.w += v3.w;
        acc.x += v4.x; acc.y += v4.y; acc.z += v4.z; acc.w += v4.w;
        acc.x += v5.x; acc.y += v5.y; acc.z += v5.z; acc.w += v5.w;
        acc.x += v6.x; acc.y += v6.y; acc.z += v6.z; acc.w += v6.w;
        acc.x += v7.x; acc.y += v7.y; acc.z += v7.z; acc.w += v7.w;
    }
    for (; j + 4 <= end; j += 4) {
        int s0 = srcs[j], s1 = srcs[j + 1], s2 = srcs[j + 2], s3 = srcs[j + 3];
        float4 v0 = t4[(size_t)s0 * FG + fg];
        float4 v1 = t4[(size_t)s1 * FG + fg];
        float4 v2 = t4[(size_t)s2 * FG + fg];
        float4 v3 = t4[(size_t)s3 * FG + fg];
        acc.x += v0.x; acc.y += v0.y; acc.z += v0.z; acc.w += v0.w;
        acc.x += v1.x; acc.y += v1.y; acc.z += v1.z; acc.w += v1.w;
        acc.x += v2.x; acc.y += v2.y; acc.z += v2.z; acc.w += v2.w;
        acc.x += v3.x; acc.y += v3.y; acc.z += v3.z; acc.w += v3.w;
    }
    for (; j < end; ++j) {
        float4 v = t4[(size_t)srcs[j] * FG + fg];
        acc.x += v.x; acc.y += v.y; acc.z += v.z; acc.w += v.w;
    }
    float dv = dinv[node];
    float4 r;
    if (MODE == 0) {
        float4 bb = ((const float4*)bias)[fg];
        r.x = acc.x * dv + bb.x; r.y = acc.y * dv + bb.y;
        r.z = acc.z * dv + bb.z; r.w = acc.w * dv + bb.w;
        r.x = (r.x > 0.f) ? r.x : 0.1f * r.x;
        r.y = (r.y > 0.f) ? r.y : 0.1f * r.y;
        r.z = (r.z > 0.f) ? r.z : 0.1f * r.z;
        r.w = (r.w > 0.f) ? r.w : 0.1f * r.w;
        r.x *= dv; r.y *= dv; r.z *= dv; r.w *= dv;
    } else {
        r.x = acc.x * dv; r.y = acc.y * dv; r.z = acc.z * dv; r.w = acc.w * dv;
    }
    ((float4*)out)[(size_t)node * FG + fg] = r;
}

// ---------------- init gbuf to -inf ----------------
__global__ void initg_kernel(float* __restrict__ g)
{
    int i = blockIdx.x * blockDim.x + threadIdx.x;
    if (i < NGRAPH * H2DIM) g[i] = -INFINITY;
}

__device__ inline void atomicMaxFloat(float* addr, float val)
{
    if (val >= 0.f) atomicMax((int*)addr, __float_as_int(val));
    else            atomicMin((unsigned int*)addr, __float_as_uint(val));
}

// ---------------- node-parallel fused gemm(32->64)+bias+segmax (proven R7) ----------------
__global__ __launch_bounds__(256) void gemmsegmax_kernel(
    const float* __restrict__ a, const float* __restrict__ W2,
    const float* __restrict__ b2, float* __restrict__ g, int n)
{
    __shared__ float Ws[H1DIM * H2DIM];     // 8 KB
    __shared__ float rows[64 * H1DIM];      // 8 KB
    __shared__ float redA[256], redB[256];
    int t = threadIdx.x;
    int base = blockIdx.x * 64;
    int lim = min(base + 64, n);
    for (int i = t; i < H1DIM * H2DIM; i += 256) Ws[i] = W2[i];
    {
        const float4* a4 = (const float4*)a;
        int nf4 = (lim - base) * (H1DIM / 4);
        for (int i = t; i < nf4; i += 256)
            ((float4*)rows)[i] = a4[(size_t)base * (H1DIM / 4) + i];
    }
    __syncthreads();
    int sub = t >> 6, f = t & 63;
    float wreg[H1DIM];
#pragma unroll
    for (int k = 0; k < H1DIM; ++k) wreg[k] = Ws[k * H2DIM + f];
    float bf = b2[f];
    int gidA = (int)(((long long)base * NGRAPH) / n);
    float mA = -INFINITY, mB = -INFINITY;
    for (int i = base + sub; i < lim; i += 4) {
        float acc = bf;
        int lr = i - base;
#pragma unroll
        for (int k = 0; k < H1DIM; k += 4) {
            float4 rv = *(float4*)&rows[lr * H1DIM + k];
            acc += rv.x * wreg[k] + rv.y * wreg[k + 1]
                 + rv.z * wreg[k + 2] + rv.w * wreg[k + 3];
        }
        int gid = (int)(((long long)i * NGRAPH) / n);
        if (gid == gidA) mA = fmaxf(mA, acc);
        else             mB = fmaxf(mB, acc);
    }
    redA[t] = mA; redB[t] = mB;
    __syncthreads();
    if (t < 64) {
        float v = fmaxf(fmaxf(redA[t], redA[t + 64]), fmaxf(redA[t + 128], redA[t + 192]));
        if (v > -INFINITY) atomicMaxFloat(&g[gidA * H2DIM + t], v);
    } else if (t < 128) {
        int f2 = t - 64;
        float v = fmaxf(fmaxf(redB[f2], redB[f2 + 64]), fmaxf(redB[f2 + 128], redB[f2 + 192]));
        int gidB = gidA + 1;
        if (gidB < NGRAPH && v > -INFINITY) atomicMaxFloat(&g[gidB * H2DIM + f2], v);
    }
}

// ---------------- tiny MLP head ----------------
__global__ __launch_bounds__(128) void mlp_kernel(
    const float* __restrict__ g,
    const float* __restrict__ l1W, const float* __restrict__ l1b,
    const float* __restrict__ l2W, const float* __restrict__ l2b,
    const float* __restrict__ l3W, const float* __restrict__ l3b,
    float* __restrict__ out)
{
    __shared__ float gin[64], z1[128], z2[64];
    int b = blockIdx.x, t = threadIdx.x;
    if (t < 64) gin[t] = g[b * 64 + t];
    __syncthreads();
    {
        float a = l1b[t];
        for (int k = 0; k < 64; ++k) a += gin[k] * l1W[k * 128 + t];
        z1[t] = (a > 0.f) ? a : 0.1f * a;
    }
    __syncthreads();
    if (t < 64) {
        float a = l2b[t];
        for (int k = 0; k < 128; ++k) a += z1[k] * l2W[k * 64 + t];
        z2[t] = (a > 0.f) ? a : 0.1f * a;
    }
    __syncthreads();
    if (t < 64) {
        float a = l3b[t];
        for (int k = 0; k < 64; ++k) a += z2[k] * l3W[k * 64 + t];
        out[b * 64 + t] = a;
    }
}

extern "C" void kernel_launch(void* const* d_in, const int* in_sizes, int n_in,
                              void* d_out, int out_size, void* d_ws, size_t ws_size,
                              hipStream_t stream) {
    const float* x   = (const float*)d_in[0];
    const int*   ei  = (const int*)d_in[1];
    const int*   src = ei;
    const int*   dst = ei + N_EDGES;
    const float* W1  = (const float*)d_in[3];
    const float* b1  = (const float*)d_in[4];
    const float* W2  = (const float*)d_in[5];
    const float* b2  = (const float*)d_in[6];
    const float* l1W = (const float*)d_in[7];
    const float* l1b = (const float*)d_in[8];
    const float* l2W = (const float*)d_in[9];
    const float* l2b = (const float*)d_in[10];
    const float* l3W = (const float*)d_in[11];
    const float* l3b = (const float*)d_in[12];
    float* outp = (float*)d_out;

    char* w = (char*)d_ws;
    size_t off = 0;
    auto alloc = [&](size_t bytes) { char* p = w + off; off += (bytes + 255) & ~(size_t)255; return p; };
    int*   countsA    = (int*)  alloc((size_t)NBLK_A * NBUCK * sizeof(int));
    int*   bucketTot  = (int*)  alloc(NBUCK * sizeof(int));
    int*   bucketBase = (int*)  alloc((NBUCK + 1) * sizeof(int));
    int*   rowptr     = (int*)  alloc((N_NODES + 1) * sizeof(int));
    float* dinv       = (float*)alloc(N_NODES * sizeof(float));
    int*   srcsorted  = (int*)  alloc(N_EDGES * sizeof(int));
    float* bufA       = (float*)alloc((size_t)N_NODES * 64 * sizeof(float));
    float* bufB       = (float*)alloc((size_t)N_NODES * 32 * sizeof(float));
    float* gbuf       = (float*)alloc(NGRAPH * H2DIM * sizeof(float));

    float* tmp1 = bufA;  // [N,32] lower half of bufA
    float* s1   = bufB;  // [N,32] = h1*dinv
    float* abuf = bufA;  // [N,32] overlay (tmp1 dead after agg1)
    // binned (E ints = 12.8 MB) overlays upper half of bufA: dead after csr_kernel.
    int* binned = (int*)(bufA + (size_t)N_NODES * 32);

    binhist_kernel<<<NBLK_A, 256, 0, stream>>>(dst, countsA, N_EDGES);
    scanAp_kernel<<<NBUCK, 64, 0, stream>>>(countsA, bucketTot);
    scanB_kernel<<<1, 512, 0, stream>>>(bucketTot, bucketBase, rowptr);
    binplace_kernel<<<NBLK_A, 256, 0, stream>>>(src, dst, countsA, bucketBase, binned, N_EDGES);
    csr_kernel<<<NBUCK, 256, 0, stream>>>(binned, bucketBase, srcsorted, rowptr, dinv, N_NODES);

    gemm_scale_kernel<F_INPUT, H1DIM><<<(N_NODES + 63) / 64, 256, 0, stream>>>(x, W1, dinv, tmp1, N_NODES);
    agg_kernel<H1DIM, 0><<<((size_t)N_NODES * (H1DIM/4) + 255) / 256, 256, 0, stream>>>(
        tmp1, rowptr, srcsorted, dinv, b1, s1, N_NODES);
    initg_kernel<<<(NGRAPH * H2DIM + 255) / 256, 256, 0, stream>>>(gbuf);
    agg_kernel<H1DIM, 1><<<((size_t)N_NODES * (H1DIM/4) + 255) / 256, 256, 0, stream>>>(
        s1, rowptr, srcsorted, dinv, b1 /*unused*/, abuf, N_NODES);

    gemmsegmax_kernel<<<(N_NODES + 63) / 64, 256, 0, stream>>>(abuf, W2, b2, gbuf, N_NODES);
    mlp_kernel<<<NGRAPH, 128, 0, stream>>>(gbuf, l1W, l1b, l2W, l2b, l3W, l3b, outp);
}

// Round 9
// 335.992 us; speedup vs baseline: 3.2778x; 1.0436x over previous
//
#include <hip/hip_runtime.h>
#include <math.h>

#define N_NODES 100000
#define N_EDGES 3200000
#define F_INPUT 128
#define H1DIM 32
#define H2DIM 64
#define NGRAPH 256
#define NACT 64
#define EPB 16384                          // edges per binning block
#define NBLK_A ((N_EDGES + EPB - 1) / EPB) // 196
#define NBUCK ((N_NODES + 255) / 256)      // 391 buckets of 256 dst nodes

typedef _Float16 half4 __attribute__((ext_vector_type(4)));
typedef _Float16 half8 __attribute__((ext_vector_type(8)));

// ---------------- CSR build: LDS-staged two-level binning (proven R5) ----------------
__global__ __launch_bounds__(256) void binhist_kernel(const int* __restrict__ dst,
                                                      int* __restrict__ countsA, int e)
{
    __shared__ int hist[NBUCK];
    for (int i = threadIdx.x; i < NBUCK; i += 256) hist[i] = 0;
    __syncthreads();
    int beg = blockIdx.x * EPB, end = min(beg + EPB, e);
    for (int i = beg + threadIdx.x; i < end; i += 256)
        atomicAdd(&hist[dst[i] >> 8], 1);
    __syncthreads();
    for (int i = threadIdx.x; i < NBUCK; i += 256)
        countsA[blockIdx.x * NBUCK + i] = hist[i];   // coalesced
}

// Parallel within-bucket scan: one wave per bucket (proven R8)
__global__ __launch_bounds__(64) void scanAp_kernel(int* __restrict__ countsA,
                                                    int* __restrict__ bucketTot)
{
    int b = blockIdx.x;
    int lane = threadIdx.x;
    int carry = 0;
    for (int r = 0; r < (NBLK_A + 63) / 64; ++r) {
        int blk = r * 64 + lane;
        int v = (blk < NBLK_A) ? countsA[blk * NBUCK + b] : 0;
        int own = v;
        for (int d = 1; d < 64; d <<= 1) {
            int t = __shfl_up(v, d);
            if (lane >= d) v += t;
        }
        if (blk < NBLK_A) countsA[blk * NBUCK + b] = v - own + carry;
        carry += __shfl(v, 63);
    }
    if (lane == 0) bucketTot[b] = carry;
}

__global__ __launch_bounds__(512) void scanB_kernel(const int* __restrict__ bucketTot,
                                                    int* __restrict__ bucketBase,
                                                    int* __restrict__ rowptr)
{
    __shared__ int sums[512];
    int b = threadIdx.x;
    int own = (b < NBUCK) ? bucketTot[b] : 0;
    sums[b] = own;
    __syncthreads();
    for (int off = 1; off < 512; off <<= 1) {
        int v = (b >= off) ? sums[b - off] : 0;
        __syncthreads();
        sums[b] += v;
        __syncthreads();
    }
    if (b < NBUCK) bucketBase[b] = sums[b] - own;
    if (b == 0) { bucketBase[NBUCK] = N_EDGES; rowptr[N_NODES] = N_EDGES; }
}

__global__ __launch_bounds__(256) void binplace_kernel(const int* __restrict__ src,
                                                       const int* __restrict__ dst,
                                                       const int* __restrict__ countsA,
                                                       const int* __restrict__ bucketBase,
                                                       int* __restrict__ binned, int e)
{
    __shared__ int cur[NBUCK];
    for (int i = threadIdx.x; i < NBUCK; i += 256)
        cur[i] = countsA[blockIdx.x * NBUCK + i] + bucketBase[i];
    __syncthreads();
    int beg = blockIdx.x * EPB, end = min(beg + EPB, e);
    for (int i = beg + threadIdx.x; i < end; i += 256) {
        int d = dst[i], s = src[i];
        int pos = atomicAdd(&cur[d >> 8], 1);          // LDS atomic
        binned[pos] = ((d & 255) << 17) | s;
    }
}

__global__ __launch_bounds__(256) void csr_kernel(const int* __restrict__ binned,
                                                  const int* __restrict__ bucketBase,
                                                  int* __restrict__ srcsorted,
                                                  int* __restrict__ rowptr,
                                                  float* __restrict__ dinv, int n)
{
    __shared__ int hist[256];
    __shared__ int sc[256];
    int b = blockIdx.x, t = threadIdx.x;
    hist[t] = 0;
    __syncthreads();
    int eBeg = bucketBase[b], eEnd = bucketBase[b + 1];
    for (int i = eBeg + t; i < eEnd; i += 256)
        atomicAdd(&hist[binned[i] >> 17], 1);
    __syncthreads();
    int own = hist[t];
    sc[t] = own;
    __syncthreads();
    for (int off = 1; off < 256; off <<= 1) {
        int v = (t >= off) ? sc[t - off] : 0;
        __syncthreads();
        sc[t] += v;
        __syncthreads();
    }
    int excl = sc[t] - own;
    int node = b * 256 + t;
    if (node < n) {
        rowptr[node] = eBeg + excl;
        dinv[node] = 1.0f / sqrtf((float)(own + 1));
    }
    hist[t] = eBeg + excl;
    __syncthreads();
    for (int i = eBeg + t; i < eEnd; i += 256) {
        int v = binned[i];
        int pos = atomicAdd(&hist[v >> 17], 1);
        srcsorted[pos] = v & 0x1FFFF;
    }
}

// ---------------- tiled GEMM + per-row dinv scale, fp16 output ----------------
__global__ __launch_bounds__(256) void gemm_scale_f16_kernel(
    const float* __restrict__ x, const float* __restrict__ W,
    const float* __restrict__ dinv, _Float16* __restrict__ out, int n)
{
    constexpr int KDIM = F_INPUT, NOUT = H1DIM;
    constexpr int ROWS = 64;
    constexpr int XS = KDIM + 4;
    constexpr int CG = NOUT / 8;   // 4
    __shared__ float xs[ROWS * XS];
    __shared__ float Ws[KDIM * NOUT];
    int t = threadIdx.x;
    int row0 = blockIdx.x * ROWS;

    for (int i = t; i < KDIM * NOUT; i += 256) Ws[i] = W[i];
    for (int i = t; i < ROWS * KDIM / 4; i += 256) {
        int r = i / (KDIM / 4);
        int kk = i % (KDIM / 4);
        float4 v = make_float4(0.f, 0.f, 0.f, 0.f);
        if (row0 + r < n) v = ((const float4*)x)[(size_t)(row0 + r) * (KDIM / 4) + kk];
        *(float4*)&xs[r * XS + kk * 4] = v;
    }
    __syncthreads();

    int tcg = t % CG;
    int trow = t / CG;
    float acc[8];
#pragma unroll
    for (int j = 0; j < 8; ++j) acc[j] = 0.f;

#pragma unroll
    for (int k = 0; k < KDIM; k += 4) {
        float4 xv = *(float4*)&xs[trow * XS + k];
#pragma unroll
        for (int kk = 0; kk < 4; ++kk) {
            float4 w0 = *(float4*)&Ws[(k + kk) * NOUT + tcg * 8];
            float4 w1 = *(float4*)&Ws[(k + kk) * NOUT + tcg * 8 + 4];
            float xk = ((float*)&xv)[kk];
            acc[0] += xk * w0.x; acc[1] += xk * w0.y;
            acc[2] += xk * w0.z; acc[3] += xk * w0.w;
            acc[4] += xk * w1.x; acc[5] += xk * w1.y;
            acc[6] += xk * w1.z; acc[7] += xk * w1.w;
        }
    }

    int row = row0 + trow;
    if (row < n) {
        float dv = dinv[row];
        half8 o;
#pragma unroll
        for (int j = 0; j < 8; ++j) o[j] = (_Float16)(acc[j] * dv);
        *(half8*)&out[(size_t)row * NOUT + tcg * 8] = o;   // 16B store
    }
}

// ---------------- gather-side aggregation, fp16 table (64 B/edge) ----------------
// MODE 0: out(half4) = leaky(acc*dinv + bias)*dinv   (s1 = h1*dinv, fp16)
// MODE 1: out(float4) = acc*dinv                     (a, fp32 for gemmsegmax)
template<int MODE, typename OutV>
__global__ __launch_bounds__(256) void agg16_kernel(
    const _Float16* __restrict__ tmp, const int* __restrict__ rowptr,
    const int* __restrict__ srcs, const float* __restrict__ dinv,
    const float* __restrict__ bias, OutV* __restrict__ out, int n)
{
    constexpr int FG = H1DIM / 4;  // 8 threads/node, 4 feats (8 B) each
    int tid = blockIdx.x * blockDim.x + threadIdx.x;
    int node = tid / FG;
    int fg = tid % FG;
    if (node >= n) return;
    int beg = rowptr[node], end = rowptr[node + 1];
    const half4* t4 = (const half4*)tmp;
    half4 sv = t4[(size_t)node * FG + fg];     // self-loop
    float ax = (float)sv.x, ay = (float)sv.y, az = (float)sv.z, aw = (float)sv.w;
    int j = beg;
    for (; j + 8 <= end; j += 8) {
        int s0 = srcs[j],     s1 = srcs[j + 1], s2 = srcs[j + 2], s3 = srcs[j + 3];
        int s4 = srcs[j + 4], s5 = srcs[j + 5], s6 = srcs[j + 6], s7 = srcs[j + 7];
        half4 v0 = t4[(size_t)s0 * FG + fg];
        half4 v1 = t4[(size_t)s1 * FG + fg];
        half4 v2 = t4[(size_t)s2 * FG + fg];
        half4 v3 = t4[(size_t)s3 * FG + fg];
        half4 v4 = t4[(size_t)s4 * FG + fg];
        half4 v5 = t4[(size_t)s5 * FG + fg];
        half4 v6 = t4[(size_t)s6 * FG + fg];
        half4 v7 = t4[(size_t)s7 * FG + fg];
        ax += (float)v0.x + (float)v1.x + (float)v2.x + (float)v3.x
            + (float)v4.x + (float)v5.x + (float)v6.x + (float)v7.x;
        ay += (float)v0.y + (float)v1.y + (float)v2.y + (float)v3.y
            + (float)v4.y + (float)v5.y + (float)v6.y + (float)v7.y;
        az += (float)v0.z + (float)v1.z + (float)v2.z + (float)v3.z
            + (float)v4.z + (float)v5.z + (float)v6.z + (float)v7.z;
        aw += (float)v0.w + (float)v1.w + (float)v2.w + (float)v3.w
            + (float)v4.w + (float)v5.w + (float)v6.w + (float)v7.w;
    }
    for (; j < end; ++j) {
        half4 v = t4[(size_t)srcs[j] * FG + fg];
        ax += (float)v.x; ay += (float)v.y; az += (float)v.z; aw += (float)v.w;
    }
    float dv = dinv[node];
    if (MODE == 0) {
        float4 bb = ((const float4*)bias)[fg];
        float rx = ax * dv + bb.x, ry = ay * dv + bb.y;
        float rz = az * dv + bb.z, rw = aw * dv + bb.w;
        rx = (rx > 0.f) ? rx : 0.1f * rx;
        ry = (ry > 0.f) ? ry : 0.1f * ry;
        rz = (rz > 0.f) ? rz : 0.1f * rz;
        rw = (rw > 0.f) ? rw : 0.1f * rw;
        half4 o;
        o.x = (_Float16)(rx * dv); o.y = (_Float16)(ry * dv);
        o.z = (_Float16)(rz * dv); o.w = (_Float16)(rw * dv);
        ((half4*)out)[(size_t)node * FG + fg] = o;
    } else {
        float4 o;
        o.x = ax * dv; o.y = ay * dv; o.z = az * dv; o.w = aw * dv;
        ((float4*)out)[(size_t)node * FG + fg] = o;
    }
}

// ---------------- init gbuf to -inf ----------------
__global__ void initg_kernel(float* __restrict__ g)
{
    int i = blockIdx.x * blockDim.x + threadIdx.x;
    if (i < NGRAPH * H2DIM) g[i] = -INFINITY;
}

__device__ inline void atomicMaxFloat(float* addr, float val)
{
    if (val >= 0.f) atomicMax((int*)addr, __float_as_int(val));
    else            atomicMin((unsigned int*)addr, __float_as_uint(val));
}

// ---------------- node-parallel fused gemm(32->64)+bias+segmax (proven R7) ----------------
__global__ __launch_bounds__(256) void gemmsegmax_kernel(
    const float* __restrict__ a, const float* __restrict__ W2,
    const float* __restrict__ b2, float* __restrict__ g, int n)
{
    __shared__ float Ws[H1DIM * H2DIM];     // 8 KB
    __shared__ float rows[64 * H1DIM];      // 8 KB
    __shared__ float redA[256], redB[256];
    int t = threadIdx.x;
    int base = blockIdx.x * 64;
    int lim = min(base + 64, n);
    for (int i = t; i < H1DIM * H2DIM; i += 256) Ws[i] = W2[i];
    {
        const float4* a4 = (const float4*)a;
        int nf4 = (lim - base) * (H1DIM / 4);
        for (int i = t; i < nf4; i += 256)
            ((float4*)rows)[i] = a4[(size_t)base * (H1DIM / 4) + i];
    }
    __syncthreads();
    int sub = t >> 6, f = t & 63;
    float wreg[H1DIM];
#pragma unroll
    for (int k = 0; k < H1DIM; ++k) wreg[k] = Ws[k * H2DIM + f];
    float bf = b2[f];
    int gidA = (int)(((long long)base * NGRAPH) / n);
    float mA = -INFINITY, mB = -INFINITY;
    for (int i = base + sub; i < lim; i += 4) {
        float acc = bf;
        int lr = i - base;
#pragma unroll
        for (int k = 0; k < H1DIM; k += 4) {
            float4 rv = *(float4*)&rows[lr * H1DIM + k];
            acc += rv.x * wreg[k] + rv.y * wreg[k + 1]
                 + rv.z * wreg[k + 2] + rv.w * wreg[k + 3];
        }
        int gid = (int)(((long long)i * NGRAPH) / n);
        if (gid == gidA) mA = fmaxf(mA, acc);
        else             mB = fmaxf(mB, acc);
    }
    redA[t] = mA; redB[t] = mB;
    __syncthreads();
    if (t < 64) {
        float v = fmaxf(fmaxf(redA[t], redA[t + 64]), fmaxf(redA[t + 128], redA[t + 192]));
        if (v > -INFINITY) atomicMaxFloat(&g[gidA * H2DIM + t], v);
    } else if (t < 128) {
        int f2 = t - 64;
        float v = fmaxf(fmaxf(redB[f2], redB[f2 + 64]), fmaxf(redB[f2 + 128], redB[f2 + 192]));
        int gidB = gidA + 1;
        if (gidB < NGRAPH && v > -INFINITY) atomicMaxFloat(&g[gidB * H2DIM + f2], v);
    }
}

// ---------------- tiny MLP head ----------------
__global__ __launch_bounds__(128) void mlp_kernel(
    const float* __restrict__ g,
    const float* __restrict__ l1W, const float* __restrict__ l1b,
    const float* __restrict__ l2W, const float* __restrict__ l2b,
    const float* __restrict__ l3W, const float* __restrict__ l3b,
    float* __restrict__ out)
{
    __shared__ float gin[64], z1[128], z2[64];
    int b = blockIdx.x, t = threadIdx.x;
    if (t < 64) gin[t] = g[b * 64 + t];
    __syncthreads();
    {
        float a = l1b[t];
        for (int k = 0; k < 64; ++k) a += gin[k] * l1W[k * 128 + t];
        z1[t] = (a > 0.f) ? a : 0.1f * a;
    }
    __syncthreads();
    if (t < 64) {
        float a = l2b[t];
        for (int k = 0; k < 128; ++k) a += z1[k] * l2W[k * 64 + t];
        z2[t] = (a > 0.f) ? a : 0.1f * a;
    }
    __syncthreads();
    if (t < 64) {
        float a = l3b[t];
        for (int k = 0; k < 64; ++k) a += z2[k] * l3W[k * 64 + t];
        out[b * 64 + t] = a;
    }
}

extern "C" void kernel_launch(void* const* d_in, const int* in_sizes, int n_in,
                              void* d_out, int out_size, void* d_ws, size_t ws_size,
                              hipStream_t stream) {
    const float* x   = (const float*)d_in[0];
    const int*   ei  = (const int*)d_in[1];
    const int*   src = ei;
    const int*   dst = ei + N_EDGES;
    const float* W1  = (const float*)d_in[3];
    const float* b1  = (const float*)d_in[4];
    const float* W2  = (const float*)d_in[5];
    const float* b2  = (const float*)d_in[6];
    const float* l1W = (const float*)d_in[7];
    const float* l1b = (const float*)d_in[8];
    const float* l2W = (const float*)d_in[9];
    const float* l2b = (const float*)d_in[10];
    const float* l3W = (const float*)d_in[11];
    const float* l3b = (const float*)d_in[12];
    float* outp = (float*)d_out;

    char* w = (char*)d_ws;
    size_t off = 0;
    auto alloc = [&](size_t bytes) { char* p = w + off; off += (bytes + 255) & ~(size_t)255; return p; };
    int*   countsA    = (int*)  alloc((size_t)NBLK_A * NBUCK * sizeof(int));
    int*   bucketTot  = (int*)  alloc(NBUCK * sizeof(int));
    int*   bucketBase = (int*)  alloc((NBUCK + 1) * sizeof(int));
    int*   rowptr     = (int*)  alloc((N_NODES + 1) * sizeof(int));
    float* dinv       = (float*)alloc(N_NODES * sizeof(float));
    int*   srcsorted  = (int*)  alloc(N_EDGES * sizeof(int));
    float* bufA       = (float*)alloc((size_t)N_NODES * 64 * sizeof(float));
    float* bufB       = (float*)alloc((size_t)N_NODES * 32 * sizeof(float));
    float* gbuf       = (float*)alloc(NGRAPH * H2DIM * sizeof(float));

    _Float16* tmp1 = (_Float16*)bufA;          // [N,32] fp16 = 6.4 MB at bufA[0..]
    _Float16* s1   = (_Float16*)bufB;          // [N,32] fp16 = h1*dinv
    float*    abuf = bufA;                     // [N,32] fp32 overlay (tmp1 dead after agg1)
    // binned (12.8 MB) overlays bufA's upper half; dead after csr_kernel (pre-gemm1).
    int* binned = (int*)(bufA + (size_t)N_NODES * 32);

    binhist_kernel<<<NBLK_A, 256, 0, stream>>>(dst, countsA, N_EDGES);
    scanAp_kernel<<<NBUCK, 64, 0, stream>>>(countsA, bucketTot);
    scanB_kernel<<<1, 512, 0, stream>>>(bucketTot, bucketBase, rowptr);
    binplace_kernel<<<NBLK_A, 256, 0, stream>>>(src, dst, countsA, bucketBase, binned, N_EDGES);
    csr_kernel<<<NBUCK, 256, 0, stream>>>(binned, bucketBase, srcsorted, rowptr, dinv, N_NODES);

    gemm_scale_f16_kernel<<<(N_NODES + 63) / 64, 256, 0, stream>>>(x, W1, dinv, tmp1, N_NODES);
    agg16_kernel<0, half4><<<((size_t)N_NODES * (H1DIM/4) + 255) / 256, 256, 0, stream>>>(
        tmp1, rowptr, srcsorted, dinv, b1, (half4*)s1, N_NODES);
    initg_kernel<<<(NGRAPH * H2DIM + 255) / 256, 256, 0, stream>>>(gbuf);
    agg16_kernel<1, float4><<<((size_t)N_NODES * (H1DIM/4) + 255) / 256, 256, 0, stream>>>(
        s1, rowptr, srcsorted, dinv, b1 /*unused*/, (float4*)abuf, N_NODES);

    gemmsegmax_kernel<<<(N_NODES + 63) / 64, 256, 0, stream>>>(abuf, W2, b2, gbuf, N_NODES);
    mlp_kernel<<<NGRAPH, 128, 0, stream>>>(gbuf, l1W, l1b, l2W, l2b, l3W, l3b, outp);
}

// Round 10
// 316.283 us; speedup vs baseline: 3.4820x; 1.0623x over previous
//
#include <hip/hip_runtime.h>
#include <math.h>

#define N_NODES 100000
#define N_EDGES 3200000
#define F_INPUT 128
#define H1DIM 32
#define H2DIM 64
#define NGRAPH 256
#define NACT 64
#define EPB 4096                           // edges per binning block (smaller -> fills 256 CUs)
#define NBLK_A ((N_EDGES + EPB - 1) / EPB) // 782
#define NBUCK ((N_NODES + 255) / 256)      // 391 buckets of 256 dst nodes

typedef _Float16 half4 __attribute__((ext_vector_type(4)));
typedef _Float16 half8 __attribute__((ext_vector_type(8)));

// ---------------- CSR build: LDS-staged two-level binning (proven R5) ----------------
__global__ __launch_bounds__(256) void binhist_kernel(const int* __restrict__ dst,
                                                      int* __restrict__ countsA, int e)
{
    __shared__ int hist[NBUCK];
    for (int i = threadIdx.x; i < NBUCK; i += 256) hist[i] = 0;
    __syncthreads();
    int beg = blockIdx.x * EPB, end = min(beg + EPB, e);
    for (int i = beg + threadIdx.x; i < end; i += 256)
        atomicAdd(&hist[dst[i] >> 8], 1);
    __syncthreads();
    for (int i = threadIdx.x; i < NBUCK; i += 256)
        countsA[blockIdx.x * NBUCK + i] = hist[i];   // coalesced
}

// Parallel within-bucket scan: one wave per bucket (proven R8)
__global__ __launch_bounds__(64) void scanAp_kernel(int* __restrict__ countsA,
                                                    int* __restrict__ bucketTot)
{
    int b = blockIdx.x;
    int lane = threadIdx.x;
    int carry = 0;
    for (int r = 0; r < (NBLK_A + 63) / 64; ++r) {
        int blk = r * 64 + lane;
        int v = (blk < NBLK_A) ? countsA[blk * NBUCK + b] : 0;
        int own = v;
        for (int d = 1; d < 64; d <<= 1) {
            int t = __shfl_up(v, d);
            if (lane >= d) v += t;
        }
        if (blk < NBLK_A) countsA[blk * NBUCK + b] = v - own + carry;
        carry += __shfl(v, 63);
    }
    if (lane == 0) bucketTot[b] = carry;
}

__global__ __launch_bounds__(512) void scanB_kernel(const int* __restrict__ bucketTot,
                                                    int* __restrict__ bucketBase,
                                                    int* __restrict__ rowptr)
{
    __shared__ int sums[512];
    int b = threadIdx.x;
    int own = (b < NBUCK) ? bucketTot[b] : 0;
    sums[b] = own;
    __syncthreads();
    for (int off = 1; off < 512; off <<= 1) {
        int v = (b >= off) ? sums[b - off] : 0;
        __syncthreads();
        sums[b] += v;
        __syncthreads();
    }
    if (b < NBUCK) bucketBase[b] = sums[b] - own;
    if (b == 0) { bucketBase[NBUCK] = N_EDGES; rowptr[N_NODES] = N_EDGES; }
}

__global__ __launch_bounds__(256) void binplace_kernel(const int* __restrict__ src,
                                                       const int* __restrict__ dst,
                                                       const int* __restrict__ countsA,
                                                       const int* __restrict__ bucketBase,
                                                       int* __restrict__ binned, int e)
{
    __shared__ int cur[NBUCK];
    for (int i = threadIdx.x; i < NBUCK; i += 256)
        cur[i] = countsA[blockIdx.x * NBUCK + i] + bucketBase[i];
    __syncthreads();
    int beg = blockIdx.x * EPB, end = min(beg + EPB, e);
    for (int i = beg + threadIdx.x; i < end; i += 256) {
        int d = dst[i], s = src[i];
        int pos = atomicAdd(&cur[d >> 8], 1);          // LDS atomic
        binned[pos] = ((d & 255) << 17) | s;
    }
}

__global__ __launch_bounds__(256) void csr_kernel(const int* __restrict__ binned,
                                                  const int* __restrict__ bucketBase,
                                                  int* __restrict__ srcsorted,
                                                  int* __restrict__ rowptr,
                                                  float* __restrict__ dinv, int n)
{
    __shared__ int hist[256];
    __shared__ int sc[256];
    int b = blockIdx.x, t = threadIdx.x;
    hist[t] = 0;
    __syncthreads();
    int eBeg = bucketBase[b], eEnd = bucketBase[b + 1];
    for (int i = eBeg + t; i < eEnd; i += 256)
        atomicAdd(&hist[binned[i] >> 17], 1);
    __syncthreads();
    int own = hist[t];
    sc[t] = own;
    __syncthreads();
    for (int off = 1; off < 256; off <<= 1) {
        int v = (t >= off) ? sc[t - off] : 0;
        __syncthreads();
        sc[t] += v;
        __syncthreads();
    }
    int excl = sc[t] - own;
    int node = b * 256 + t;
    if (node < n) {
        rowptr[node] = eBeg + excl;
        dinv[node] = 1.0f / sqrtf((float)(own + 1));
    }
    hist[t] = eBeg + excl;
    __syncthreads();
    for (int i = eBeg + t; i < eEnd; i += 256) {
        int v = binned[i];
        int pos = atomicAdd(&hist[v >> 17], 1);
        srcsorted[pos] = v & 0x1FFFF;
    }
}

// ---------------- gemm1 + dinv scale, fp16 out, K-split staging ----------------
// LDS: xs 64x68 fp32 (17.4 KB) + Ws 64x32 fp32 (8 KB) = 25.6 KB -> 6 blocks/CU.
// Accumulation order identical to the monolithic version (k ascending).
__global__ __launch_bounds__(256) void gemm_scale_f16_kernel(
    const float* __restrict__ x, const float* __restrict__ W,
    const float* __restrict__ dinv, _Float16* __restrict__ out, int n)
{
    constexpr int KDIM = F_INPUT, NOUT = H1DIM;
    constexpr int KH = 64;          // K half
    constexpr int ROWS = 64;
    constexpr int XS = KH + 4;
    constexpr int CG = NOUT / 8;    // 4 threads per row
    __shared__ float xs[ROWS * XS];     // 17408 B
    __shared__ float Ws[KH * NOUT];     // 8192 B
    int t = threadIdx.x;
    int row0 = blockIdx.x * ROWS;
    int tcg = t % CG;
    int trow = t / CG;

    float acc[8];
#pragma unroll
    for (int j = 0; j < 8; ++j) acc[j] = 0.f;

    for (int h = 0; h < 2; ++h) {
        if (h) __syncthreads();   // protect LDS reuse across halves
        // stage W half: W[h*64 + r][c], 2048 floats
        for (int i = t; i < KH * NOUT; i += 256) Ws[i] = W[h * KH * NOUT + i];
        // stage x half: 64 rows x 16 float4
        for (int i = t; i < ROWS * (KH / 4); i += 256) {
            int r = i / (KH / 4);
            int kk = i % (KH / 4);
            float4 v = make_float4(0.f, 0.f, 0.f, 0.f);
            if (row0 + r < n)
                v = ((const float4*)x)[(size_t)(row0 + r) * (KDIM / 4) + h * (KH / 4) + kk];
            *(float4*)&xs[r * XS + kk * 4] = v;
        }
        __syncthreads();

#pragma unroll
        for (int k = 0; k < KH; k += 4) {
            float4 xv = *(float4*)&xs[trow * XS + k];
#pragma unroll
            for (int kk = 0; kk < 4; ++kk) {
                float4 w0 = *(float4*)&Ws[(k + kk) * NOUT + tcg * 8];
                float4 w1 = *(float4*)&Ws[(k + kk) * NOUT + tcg * 8 + 4];
                float xk = ((float*)&xv)[kk];
                acc[0] += xk * w0.x; acc[1] += xk * w0.y;
                acc[2] += xk * w0.z; acc[3] += xk * w0.w;
                acc[4] += xk * w1.x; acc[5] += xk * w1.y;
                acc[6] += xk * w1.z; acc[7] += xk * w1.w;
            }
        }
    }

    int row = row0 + trow;
    if (row < n) {
        float dv = dinv[row];
        half8 o;
#pragma unroll
        for (int j = 0; j < 8; ++j) o[j] = (_Float16)(acc[j] * dv);
        *(half8*)&out[(size_t)row * NOUT + tcg * 8] = o;   // 16B store
    }
}

// ---------------- gather-side aggregation, fp16 table (proven R9) ----------------
// MODE 0: out(half4) = leaky(acc*dinv + bias)*dinv   (s1 = h1*dinv, fp16)
// MODE 1: out(float4) = acc*dinv                     (a, fp32 for gemmsegmax)
template<int MODE, typename OutV>
__global__ __launch_bounds__(256) void agg16_kernel(
    const _Float16* __restrict__ tmp, const int* __restrict__ rowptr,
    const int* __restrict__ srcs, const float* __restrict__ dinv,
    const float* __restrict__ bias, OutV* __restrict__ out, int n)
{
    constexpr int FG = H1DIM / 4;  // 8 threads/node, 4 feats (8 B) each
    int tid = blockIdx.x * blockDim.x + threadIdx.x;
    int node = tid / FG;
    int fg = tid % FG;
    if (node >= n) return;
    int beg = rowptr[node], end = rowptr[node + 1];
    const half4* t4 = (const half4*)tmp;
    half4 sv = t4[(size_t)node * FG + fg];     // self-loop
    float ax = (float)sv.x, ay = (float)sv.y, az = (float)sv.z, aw = (float)sv.w;
    int j = beg;
    for (; j + 8 <= end; j += 8) {
        int s0 = srcs[j],     s1 = srcs[j + 1], s2 = srcs[j + 2], s3 = srcs[j + 3];
        int s4 = srcs[j + 4], s5 = srcs[j + 5], s6 = srcs[j + 6], s7 = srcs[j + 7];
        half4 v0 = t4[(size_t)s0 * FG + fg];
        half4 v1 = t4[(size_t)s1 * FG + fg];
        half4 v2 = t4[(size_t)s2 * FG + fg];
        half4 v3 = t4[(size_t)s3 * FG + fg];
        half4 v4 = t4[(size_t)s4 * FG + fg];
        half4 v5 = t4[(size_t)s5 * FG + fg];
        half4 v6 = t4[(size_t)s6 * FG + fg];
        half4 v7 = t4[(size_t)s7 * FG + fg];
        ax += (float)v0.x + (float)v1.x + (float)v2.x + (float)v3.x
            + (float)v4.x + (float)v5.x + (float)v6.x + (float)v7.x;
        ay += (float)v0.y + (float)v1.y + (float)v2.y + (float)v3.y
            + (float)v4.y + (float)v5.y + (float)v6.y + (float)v7.y;
        az += (float)v0.z + (float)v1.z + (float)v2.z + (float)v3.z
            + (float)v4.z + (float)v5.z + (float)v6.z + (float)v7.z;
        aw += (float)v0.w + (float)v1.w + (float)v2.w + (float)v3.w
            + (float)v4.w + (float)v5.w + (float)v6.w + (float)v7.w;
    }
    for (; j < end; ++j) {
        half4 v = t4[(size_t)srcs[j] * FG + fg];
        ax += (float)v.x; ay += (float)v.y; az += (float)v.z; aw += (float)v.w;
    }
    float dv = dinv[node];
    if (MODE == 0) {
        float4 bb = ((const float4*)bias)[fg];
        float rx = ax * dv + bb.x, ry = ay * dv + bb.y;
        float rz = az * dv + bb.z, rw = aw * dv + bb.w;
        rx = (rx > 0.f) ? rx : 0.1f * rx;
        ry = (ry > 0.f) ? ry : 0.1f * ry;
        rz = (rz > 0.f) ? rz : 0.1f * rz;
        rw = (rw > 0.f) ? rw : 0.1f * rw;
        half4 o;
        o.x = (_Float16)(rx * dv); o.y = (_Float16)(ry * dv);
        o.z = (_Float16)(rz * dv); o.w = (_Float16)(rw * dv);
        ((half4*)out)[(size_t)node * FG + fg] = o;
    } else {
        float4 o;
        o.x = ax * dv; o.y = ay * dv; o.z = az * dv; o.w = aw * dv;
        ((float4*)out)[(size_t)node * FG + fg] = o;
    }
}

// ---------------- init gbuf to -inf ----------------
__global__ void initg_kernel(float* __restrict__ g)
{
    int i = blockIdx.x * blockDim.x + threadIdx.x;
    if (i < NGRAPH * H2DIM) g[i] = -INFINITY;
}

__device__ inline void atomicMaxFloat(float* addr, float val)
{
    if (val >= 0.f) atomicMax((int*)addr, __float_as_int(val));
    else            atomicMin((unsigned int*)addr, __float_as_uint(val));
}

// ---------------- node-parallel fused gemm(32->64)+bias+segmax (proven R7) ----------------
__global__ __launch_bounds__(256) void gemmsegmax_kernel(
    const float* __restrict__ a, const float* __restrict__ W2,
    const float* __restrict__ b2, float* __restrict__ g, int n)
{
    __shared__ float Ws[H1DIM * H2DIM];     // 8 KB
    __shared__ float rows[64 * H1DIM];      // 8 KB
    __shared__ float redA[256], redB[256];
    int t = threadIdx.x;
    int base = blockIdx.x * 64;
    int lim = min(base + 64, n);
    for (int i = t; i < H1DIM * H2DIM; i += 256) Ws[i] = W2[i];
    {
        const float4* a4 = (const float4*)a;
        int nf4 = (lim - base) * (H1DIM / 4);
        for (int i = t; i < nf4; i += 256)
            ((float4*)rows)[i] = a4[(size_t)base * (H1DIM / 4) + i];
    }
    __syncthreads();
    int sub = t >> 6, f = t & 63;
    float wreg[H1DIM];
#pragma unroll
    for (int k = 0; k < H1DIM; ++k) wreg[k] = Ws[k * H2DIM + f];
    float bf = b2[f];
    int gidA = (int)(((long long)base * NGRAPH) / n);
    float mA = -INFINITY, mB = -INFINITY;
    for (int i = base + sub; i < lim; i += 4) {
        float acc = bf;
        int lr = i - base;
#pragma unroll
        for (int k = 0; k < H1DIM; k += 4) {
            float4 rv = *(float4*)&rows[lr * H1DIM + k];
            acc += rv.x * wreg[k] + rv.y * wreg[k + 1]
                 + rv.z * wreg[k + 2] + rv.w * wreg[k + 3];
        }
        int gid = (int)(((long long)i * NGRAPH) / n);
        if (gid == gidA) mA = fmaxf(mA, acc);
        else             mB = fmaxf(mB, acc);
    }
    redA[t] = mA; redB[t] = mB;
    __syncthreads();
    if (t < 64) {
        float v = fmaxf(fmaxf(redA[t], redA[t + 64]), fmaxf(redA[t + 128], redA[t + 192]));
        if (v > -INFINITY) atomicMaxFloat(&g[gidA * H2DIM + t], v);
    } else if (t < 128) {
        int f2 = t - 64;
        float v = fmaxf(fmaxf(redB[f2], redB[f2 + 64]), fmaxf(redB[f2 + 128], redB[f2 + 192]));
        int gidB = gidA + 1;
        if (gidB < NGRAPH && v > -INFINITY) atomicMaxFloat(&g[gidB * H2DIM + f2], v);
    }
}

// ---------------- tiny MLP head ----------------
__global__ __launch_bounds__(128) void mlp_kernel(
    const float* __restrict__ g,
    const float* __restrict__ l1W, const float* __restrict__ l1b,
    const float* __restrict__ l2W, const float* __restrict__ l2b,
    const float* __restrict__ l3W, const float* __restrict__ l3b,
    float* __restrict__ out)
{
    __shared__ float gin[64], z1[128], z2[64];
    int b = blockIdx.x, t = threadIdx.x;
    if (t < 64) gin[t] = g[b * 64 + t];
    __syncthreads();
    {
        float a = l1b[t];
        for (int k = 0; k < 64; ++k) a += gin[k] * l1W[k * 128 + t];
        z1[t] = (a > 0.f) ? a : 0.1f * a;
    }
    __syncthreads();
    if (t < 64) {
        float a = l2b[t];
        for (int k = 0; k < 128; ++k) a += z1[k] * l2W[k * 64 + t];
        z2[t] = (a > 0.f) ? a : 0.1f * a;
    }
    __syncthreads();
    if (t < 64) {
        float a = l3b[t];
        for (int k = 0; k < 64; ++k) a += z2[k] * l3W[k * 64 + t];
        out[b * 64 + t] = a;
    }
}

extern "C" void kernel_launch(void* const* d_in, const int* in_sizes, int n_in,
                              void* d_out, int out_size, void* d_ws, size_t ws_size,
                              hipStream_t stream) {
    const float* x   = (const float*)d_in[0];
    const int*   ei  = (const int*)d_in[1];
    const int*   src = ei;
    const int*   dst = ei + N_EDGES;
    const float* W1  = (const float*)d_in[3];
    const float* b1  = (const float*)d_in[4];
    const float* W2  = (const float*)d_in[5];
    const float* b2  = (const float*)d_in[6];
    const float* l1W = (const float*)d_in[7];
    const float* l1b = (const float*)d_in[8];
    const float* l2W = (const float*)d_in[9];
    const float* l2b = (const float*)d_in[10];
    const float* l3W = (const float*)d_in[11];
    const float* l3b = (const float*)d_in[12];
    float* outp = (float*)d_out;

    char* w = (char*)d_ws;
    size_t off = 0;
    auto alloc = [&](size_t bytes) { char* p = w + off; off += (bytes + 255) & ~(size_t)255; return p; };
    int*   countsA    = (int*)  alloc((size_t)NBLK_A * NBUCK * sizeof(int));  // 1.22 MB
    int*   bucketTot  = (int*)  alloc(NBUCK * sizeof(int));
    int*   bucketBase = (int*)  alloc((NBUCK + 1) * sizeof(int));
    int*   rowptr     = (int*)  alloc((N_NODES + 1) * sizeof(int));
    float* dinv       = (float*)alloc(N_NODES * sizeof(float));
    int*   srcsorted  = (int*)  alloc(N_EDGES * sizeof(int));
    float* bufA       = (float*)alloc((size_t)N_NODES * 64 * sizeof(float));
    float* bufB       = (float*)alloc((size_t)N_NODES * 32 * sizeof(float));
    float* gbuf       = (float*)alloc(NGRAPH * H2DIM * sizeof(float));

    _Float16* tmp1 = (_Float16*)bufA;          // [N,32] fp16 = 6.4 MB at bufA[0..]
    _Float16* s1   = (_Float16*)bufB;          // [N,32] fp16 = h1*dinv
    float*    abuf = bufA;                     // [N,32] fp32 overlay (tmp1 dead after agg1)
    // binned (12.8 MB) overlays bufA's upper half; dead after csr_kernel (pre-gemm1).
    int* binned = (int*)(bufA + (size_t)N_NODES * 32);

    binhist_kernel<<<NBLK_A, 256, 0, stream>>>(dst, countsA, N_EDGES);
    scanAp_kernel<<<NBUCK, 64, 0, stream>>>(countsA, bucketTot);
    scanB_kernel<<<1, 512, 0, stream>>>(bucketTot, bucketBase, rowptr);
    binplace_kernel<<<NBLK_A, 256, 0, stream>>>(src, dst, countsA, bucketBase, binned, N_EDGES);
    csr_kernel<<<NBUCK, 256, 0, stream>>>(binned, bucketBase, srcsorted, rowptr, dinv, N_NODES);

    gemm_scale_f16_kernel<<<(N_NODES + 63) / 64, 256, 0, stream>>>(x, W1, dinv, tmp1, N_NODES);
    agg16_kernel<0, half4><<<((size_t)N_NODES * (H1DIM/4) + 255) / 256, 256, 0, stream>>>(
        tmp1, rowptr, srcsorted, dinv, b1, (half4*)s1, N_NODES);
    initg_kernel<<<(NGRAPH * H2DIM + 255) / 256, 256, 0, stream>>>(gbuf);
    agg16_kernel<1, float4><<<((size_t)N_NODES * (H1DIM/4) + 255) / 256, 256, 0, stream>>>(
        s1, rowptr, srcsorted, dinv, b1 /*unused*/, (float4*)abuf, N_NODES);

    gemmsegmax_kernel<<<(N_NODES + 63) / 64, 256, 0, stream>>>(abuf, W2, b2, gbuf, N_NODES);
    mlp_kernel<<<NGRAPH, 128, 0, stream>>>(gbuf, l1W, l1b, l2W, l2b, l3W, l3b, outp);
}

// Round 11
// 297.626 us; speedup vs baseline: 3.7003x; 1.0627x over previous
//
#include <hip/hip_runtime.h>
#include <math.h>

#define N_NODES 100000
#define N_EDGES 3200000
#define F_INPUT 128
#define H1DIM 32
#define H2DIM 64
#define NGRAPH 256
#define NACT 64
#define EPB 16384                          // edges per binning block (long runs -> full lines)
#define NBLK_A ((N_EDGES + EPB - 1) / EPB) // 196
#define NBUCK ((N_NODES + 255) / 256)      // 391 buckets of 256 dst nodes

typedef _Float16 half4 __attribute__((ext_vector_type(4)));
typedef _Float16 half8 __attribute__((ext_vector_type(8)));

// ---------------- CSR build: LDS-staged two-level binning ----------------
// 1024 threads/block: 16 waves/CU latency hiding at 196-block grid.
__global__ __launch_bounds__(1024) void binhist_kernel(const int* __restrict__ dst,
                                                       int* __restrict__ countsA, int e)
{
    __shared__ int hist[NBUCK];
    for (int i = threadIdx.x; i < NBUCK; i += 1024) hist[i] = 0;
    __syncthreads();
    int beg = blockIdx.x * EPB, end = min(beg + EPB, e);
    for (int i = beg + threadIdx.x; i < end; i += 1024)
        atomicAdd(&hist[dst[i] >> 8], 1);
    __syncthreads();
    for (int i = threadIdx.x; i < NBUCK; i += 1024)
        countsA[blockIdx.x * NBUCK + i] = hist[i];   // coalesced
}

// Parallel within-bucket scan: one wave per bucket (proven R8)
__global__ __launch_bounds__(64) void scanAp_kernel(int* __restrict__ countsA,
                                                    int* __restrict__ bucketTot)
{
    int b = blockIdx.x;
    int lane = threadIdx.x;
    int carry = 0;
    for (int r = 0; r < (NBLK_A + 63) / 64; ++r) {
        int blk = r * 64 + lane;
        int v = (blk < NBLK_A) ? countsA[blk * NBUCK + b] : 0;
        int own = v;
        for (int d = 1; d < 64; d <<= 1) {
            int t = __shfl_up(v, d);
            if (lane >= d) v += t;
        }
        if (blk < NBLK_A) countsA[blk * NBUCK + b] = v - own + carry;
        carry += __shfl(v, 63);
    }
    if (lane == 0) bucketTot[b] = carry;
}

// Top scan over bucket totals + gbuf -inf init fused (one fewer launch).
__global__ __launch_bounds__(512) void scanB_kernel(const int* __restrict__ bucketTot,
                                                    int* __restrict__ bucketBase,
                                                    int* __restrict__ rowptr,
                                                    float* __restrict__ g)
{
    __shared__ int sums[512];
    int b = threadIdx.x;
    int own = (b < NBUCK) ? bucketTot[b] : 0;
    sums[b] = own;
    __syncthreads();
    for (int off = 1; off < 512; off <<= 1) {
        int v = (b >= off) ? sums[b - off] : 0;
        __syncthreads();
        sums[b] += v;
        __syncthreads();
    }
    if (b < NBUCK) bucketBase[b] = sums[b] - own;
    if (b == 0) { bucketBase[NBUCK] = N_EDGES; rowptr[N_NODES] = N_EDGES; }
    for (int i = b; i < NGRAPH * H2DIM; i += 512) g[i] = -INFINITY;
}

__global__ __launch_bounds__(1024) void binplace_kernel(const int* __restrict__ src,
                                                        const int* __restrict__ dst,
                                                        const int* __restrict__ countsA,
                                                        const int* __restrict__ bucketBase,
                                                        int* __restrict__ binned, int e)
{
    __shared__ int cur[NBUCK];
    for (int i = threadIdx.x; i < NBUCK; i += 1024)
        cur[i] = countsA[blockIdx.x * NBUCK + i] + bucketBase[i];
    __syncthreads();
    int beg = blockIdx.x * EPB, end = min(beg + EPB, e);
    for (int i = beg + threadIdx.x; i < end; i += 1024) {
        int d = dst[i], s = src[i];
        int pos = atomicAdd(&cur[d >> 8], 1);          // LDS atomic
        binned[pos] = ((d & 255) << 17) | s;
    }
}

__global__ __launch_bounds__(256) void csr_kernel(const int* __restrict__ binned,
                                                  const int* __restrict__ bucketBase,
                                                  int* __restrict__ srcsorted,
                                                  int* __restrict__ rowptr,
                                                  float* __restrict__ dinv, int n)
{
    __shared__ int hist[256];
    __shared__ int sc[256];
    int b = blockIdx.x, t = threadIdx.x;
    hist[t] = 0;
    __syncthreads();
    int eBeg = bucketBase[b], eEnd = bucketBase[b + 1];
    for (int i = eBeg + t; i < eEnd; i += 256)
        atomicAdd(&hist[binned[i] >> 17], 1);
    __syncthreads();
    int own = hist[t];
    sc[t] = own;
    __syncthreads();
    for (int off = 1; off < 256; off <<= 1) {
        int v = (t >= off) ? sc[t - off] : 0;
        __syncthreads();
        sc[t] += v;
        __syncthreads();
    }
    int excl = sc[t] - own;
    int node = b * 256 + t;
    if (node < n) {
        rowptr[node] = eBeg + excl;
        dinv[node] = 1.0f / sqrtf((float)(own + 1));
    }
    hist[t] = eBeg + excl;
    __syncthreads();
    for (int i = eBeg + t; i < eEnd; i += 256) {
        int v = binned[i];
        int pos = atomicAdd(&hist[v >> 17], 1);
        srcsorted[pos] = v & 0x1FFFF;
    }
}

// ---------------- gemm1 + dinv scale, fp16 out, K-split staging (proven R10) ----------------
__global__ __launch_bounds__(256) void gemm_scale_f16_kernel(
    const float* __restrict__ x, const float* __restrict__ W,
    const float* __restrict__ dinv, _Float16* __restrict__ out, int n)
{
    constexpr int KDIM = F_INPUT, NOUT = H1DIM;
    constexpr int KH = 64;          // K half
    constexpr int ROWS = 64;
    constexpr int XS = KH + 4;
    constexpr int CG = NOUT / 8;    // 4 threads per row
    __shared__ float xs[ROWS * XS];     // 17408 B
    __shared__ float Ws[KH * NOUT];     // 8192 B
    int t = threadIdx.x;
    int row0 = blockIdx.x * ROWS;
    int tcg = t % CG;
    int trow = t / CG;

    float acc[8];
#pragma unroll
    for (int j = 0; j < 8; ++j) acc[j] = 0.f;

    for (int h = 0; h < 2; ++h) {
        if (h) __syncthreads();
        for (int i = t; i < KH * NOUT; i += 256) Ws[i] = W[h * KH * NOUT + i];
        for (int i = t; i < ROWS * (KH / 4); i += 256) {
            int r = i / (KH / 4);
            int kk = i % (KH / 4);
            float4 v = make_float4(0.f, 0.f, 0.f, 0.f);
            if (row0 + r < n)
                v = ((const float4*)x)[(size_t)(row0 + r) * (KDIM / 4) + h * (KH / 4) + kk];
            *(float4*)&xs[r * XS + kk * 4] = v;
        }
        __syncthreads();

#pragma unroll
        for (int k = 0; k < KH; k += 4) {
            float4 xv = *(float4*)&xs[trow * XS + k];
#pragma unroll
            for (int kk = 0; kk < 4; ++kk) {
                float4 w0 = *(float4*)&Ws[(k + kk) * NOUT + tcg * 8];
                float4 w1 = *(float4*)&Ws[(k + kk) * NOUT + tcg * 8 + 4];
                float xk = ((float*)&xv)[kk];
                acc[0] += xk * w0.x; acc[1] += xk * w0.y;
                acc[2] += xk * w0.z; acc[3] += xk * w0.w;
                acc[4] += xk * w1.x; acc[5] += xk * w1.y;
                acc[6] += xk * w1.z; acc[7] += xk * w1.w;
            }
        }
    }

    int row = row0 + trow;
    if (row < n) {
        float dv = dinv[row];
        half8 o;
#pragma unroll
        for (int j = 0; j < 8; ++j) o[j] = (_Float16)(acc[j] * dv);
        *(half8*)&out[(size_t)row * NOUT + tcg * 8] = o;   // 16B store
    }
}

// ---------------- gather-side aggregation, fp16 table (proven R9) ----------------
template<int MODE, typename OutV>
__global__ __launch_bounds__(256) void agg16_kernel(
    const _Float16* __restrict__ tmp, const int* __restrict__ rowptr,
    const int* __restrict__ srcs, const float* __restrict__ dinv,
    const float* __restrict__ bias, OutV* __restrict__ out, int n)
{
    constexpr int FG = H1DIM / 4;  // 8 threads/node, 4 feats (8 B) each
    int tid = blockIdx.x * blockDim.x + threadIdx.x;
    int node = tid / FG;
    int fg = tid % FG;
    if (node >= n) return;
    int beg = rowptr[node], end = rowptr[node + 1];
    const half4* t4 = (const half4*)tmp;
    half4 sv = t4[(size_t)node * FG + fg];     // self-loop
    float ax = (float)sv.x, ay = (float)sv.y, az = (float)sv.z, aw = (float)sv.w;
    int j = beg;
    for (; j + 8 <= end; j += 8) {
        int s0 = srcs[j],     s1 = srcs[j + 1], s2 = srcs[j + 2], s3 = srcs[j + 3];
        int s4 = srcs[j + 4], s5 = srcs[j + 5], s6 = srcs[j + 6], s7 = srcs[j + 7];
        half4 v0 = t4[(size_t)s0 * FG + fg];
        half4 v1 = t4[(size_t)s1 * FG + fg];
        half4 v2 = t4[(size_t)s2 * FG + fg];
        half4 v3 = t4[(size_t)s3 * FG + fg];
        half4 v4 = t4[(size_t)s4 * FG + fg];
        half4 v5 = t4[(size_t)s5 * FG + fg];
        half4 v6 = t4[(size_t)s6 * FG + fg];
        half4 v7 = t4[(size_t)s7 * FG + fg];
        ax += (float)v0.x + (float)v1.x + (float)v2.x + (float)v3.x
            + (float)v4.x + (float)v5.x + (float)v6.x + (float)v7.x;
        ay += (float)v0.y + (float)v1.y + (float)v2.y + (float)v3.y
            + (float)v4.y + (float)v5.y + (float)v6.y + (float)v7.y;
        az += (float)v0.z + (float)v1.z + (float)v2.z + (float)v3.z
            + (float)v4.z + (float)v5.z + (float)v6.z + (float)v7.z;
        aw += (float)v0.w + (float)v1.w + (float)v2.w + (float)v3.w
            + (float)v4.w + (float)v5.w + (float)v6.w + (float)v7.w;
    }
    for (; j < end; ++j) {
        half4 v = t4[(size_t)srcs[j] * FG + fg];
        ax += (float)v.x; ay += (float)v.y; az += (float)v.z; aw += (float)v.w;
    }
    float dv = dinv[node];
    if (MODE == 0) {
        float4 bb = ((const float4*)bias)[fg];
        float rx = ax * dv + bb.x, ry = ay * dv + bb.y;
        float rz = az * dv + bb.z, rw = aw * dv + bb.w;
        rx = (rx > 0.f) ? rx : 0.1f * rx;
        ry = (ry > 0.f) ? ry : 0.1f * ry;
        rz = (rz > 0.f) ? rz : 0.1f * rz;
        rw = (rw > 0.f) ? rw : 0.1f * rw;
        half4 o;
        o.x = (_Float16)(rx * dv); o.y = (_Float16)(ry * dv);
        o.z = (_Float16)(rz * dv); o.w = (_Float16)(rw * dv);
        ((half4*)out)[(size_t)node * FG + fg] = o;
    } else {
        float4 o;
        o.x = ax * dv; o.y = ay * dv; o.z = az * dv; o.w = aw * dv;
        ((float4*)out)[(size_t)node * FG + fg] = o;
    }
}

__device__ inline void atomicMaxFloat(float* addr, float val)
{
    if (val >= 0.f) atomicMax((int*)addr, __float_as_int(val));
    else            atomicMin((unsigned int*)addr, __float_as_uint(val));
}

// ---------------- node-parallel fused gemm(32->64)+bias+segmax (proven R7) ----------------
__global__ __launch_bounds__(256) void gemmsegmax_kernel(
    const float* __restrict__ a, const float* __restrict__ W2,
    const float* __restrict__ b2, float* __restrict__ g, int n)
{
    __shared__ float Ws[H1DIM * H2DIM];     // 8 KB
    __shared__ float rows[64 * H1DIM];      // 8 KB
    __shared__ float redA[256], redB[256];
    int t = threadIdx.x;
    int base = blockIdx.x * 64;
    int lim = min(base + 64, n);
    for (int i = t; i < H1DIM * H2DIM; i += 256) Ws[i] = W2[i];
    {
        const float4* a4 = (const float4*)a;
        int nf4 = (lim - base) * (H1DIM / 4);
        for (int i = t; i < nf4; i += 256)
            ((float4*)rows)[i] = a4[(size_t)base * (H1DIM / 4) + i];
    }
    __syncthreads();
    int sub = t >> 6, f = t & 63;
    float wreg[H1DIM];
#pragma unroll
    for (int k = 0; k < H1DIM; ++k) wreg[k] = Ws[k * H2DIM + f];
    float bf = b2[f];
    int gidA = (int)(((long long)base * NGRAPH) / n);
    float mA = -INFINITY, mB = -INFINITY;
    for (int i = base + sub; i < lim; i += 4) {
        float acc = bf;
        int lr = i - base;
#pragma unroll
        for (int k = 0; k < H1DIM; k += 4) {
            float4 rv = *(float4*)&rows[lr * H1DIM + k];
            acc += rv.x * wreg[k] + rv.y * wreg[k + 1]
                 + rv.z * wreg[k + 2] + rv.w * wreg[k + 3];
        }
        int gid = (int)(((long long)i * NGRAPH) / n);
        if (gid == gidA) mA = fmaxf(mA, acc);
        else             mB = fmaxf(mB, acc);
    }
    redA[t] = mA; redB[t] = mB;
    __syncthreads();
    if (t < 64) {
        float v = fmaxf(fmaxf(redA[t], redA[t + 64]), fmaxf(redA[t + 128], redA[t + 192]));
        if (v > -INFINITY) atomicMaxFloat(&g[gidA * H2DIM + t], v);
    } else if (t < 128) {
        int f2 = t - 64;
        float v = fmaxf(fmaxf(redB[f2], redB[f2 + 64]), fmaxf(redB[f2 + 128], redB[f2 + 192]));
        int gidB = gidA + 1;
        if (gidB < NGRAPH && v > -INFINITY) atomicMaxFloat(&g[gidB * H2DIM + f2], v);
    }
}

// ---------------- tiny MLP head ----------------
__global__ __launch_bounds__(128) void mlp_kernel(
    const float* __restrict__ g,
    const float* __restrict__ l1W, const float* __restrict__ l1b,
    const float* __restrict__ l2W, const float* __restrict__ l2b,
    const float* __restrict__ l3W, const float* __restrict__ l3b,
    float* __restrict__ out)
{
    __shared__ float gin[64], z1[128], z2[64];
    int b = blockIdx.x, t = threadIdx.x;
    if (t < 64) gin[t] = g[b * 64 + t];
    __syncthreads();
    {
        float a = l1b[t];
        for (int k = 0; k < 64; ++k) a += gin[k] * l1W[k * 128 + t];
        z1[t] = (a > 0.f) ? a : 0.1f * a;
    }
    __syncthreads();
    if (t < 64) {
        float a = l2b[t];
        for (int k = 0; k < 128; ++k) a += z1[k] * l2W[k * 64 + t];
        z2[t] = (a > 0.f) ? a : 0.1f * a;
    }
    __syncthreads();
    if (t < 64) {
        float a = l3b[t];
        for (int k = 0; k < 64; ++k) a += z2[k] * l3W[k * 64 + t];
        out[b * 64 + t] = a;
    }
}

extern "C" void kernel_launch(void* const* d_in, const int* in_sizes, int n_in,
                              void* d_out, int out_size, void* d_ws, size_t ws_size,
                              hipStream_t stream) {
    const float* x   = (const float*)d_in[0];
    const int*   ei  = (const int*)d_in[1];
    const int*   src = ei;
    const int*   dst = ei + N_EDGES;
    const float* W1  = (const float*)d_in[3];
    const float* b1  = (const float*)d_in[4];
    const float* W2  = (const float*)d_in[5];
    const float* b2  = (const float*)d_in[6];
    const float* l1W = (const float*)d_in[7];
    const float* l1b = (const float*)d_in[8];
    const float* l2W = (const float*)d_in[9];
    const float* l2b = (const float*)d_in[10];
    const float* l3W = (const float*)d_in[11];
    const float* l3b = (const float*)d_in[12];
    float* outp = (float*)d_out;

    char* w = (char*)d_ws;
    size_t off = 0;
    auto alloc = [&](size_t bytes) { char* p = w + off; off += (bytes + 255) & ~(size_t)255; return p; };
    int*   countsA    = (int*)  alloc((size_t)NBLK_A * NBUCK * sizeof(int));
    int*   bucketTot  = (int*)  alloc(NBUCK * sizeof(int));
    int*   bucketBase = (int*)  alloc((NBUCK + 1) * sizeof(int));
    int*   rowptr     = (int*)  alloc((N_NODES + 1) * sizeof(int));
    float* dinv       = (float*)alloc(N_NODES * sizeof(float));
    int*   srcsorted  = (int*)  alloc(N_EDGES * sizeof(int));
    float* bufA       = (float*)alloc((size_t)N_NODES * 64 * sizeof(float));
    float* bufB       = (float*)alloc((size_t)N_NODES * 32 * sizeof(float));
    float* gbuf       = (float*)alloc(NGRAPH * H2DIM * sizeof(float));

    _Float16* tmp1 = (_Float16*)bufA;          // [N,32] fp16 = 6.4 MB at bufA[0..]
    _Float16* s1   = (_Float16*)bufB;          // [N,32] fp16 = h1*dinv
    float*    abuf = bufA;                     // [N,32] fp32 overlay (tmp1 dead after agg1)
    // binned (12.8 MB) overlays bufA's upper half; dead after csr_kernel (pre-gemm1).
    int* binned = (int*)(bufA + (size_t)N_NODES * 32);

    binhist_kernel<<<NBLK_A, 1024, 0, stream>>>(dst, countsA, N_EDGES);
    scanAp_kernel<<<NBUCK, 64, 0, stream>>>(countsA, bucketTot);
    scanB_kernel<<<1, 512, 0, stream>>>(bucketTot, bucketBase, rowptr, gbuf);
    binplace_kernel<<<NBLK_A, 1024, 0, stream>>>(src, dst, countsA, bucketBase, binned, N_EDGES);
    csr_kernel<<<NBUCK, 256, 0, stream>>>(binned, bucketBase, srcsorted, rowptr, dinv, N_NODES);

    gemm_scale_f16_kernel<<<(N_NODES + 63) / 64, 256, 0, stream>>>(x, W1, dinv, tmp1, N_NODES);
    agg16_kernel<0, half4><<<((size_t)N_NODES * (H1DIM/4) + 255) / 256, 256, 0, stream>>>(
        tmp1, rowptr, srcsorted, dinv, b1, (half4*)s1, N_NODES);
    agg16_kernel<1, float4><<<((size_t)N_NODES * (H1DIM/4) + 255) / 256, 256, 0, stream>>>(
        s1, rowptr, srcsorted, dinv, b1 /*unused*/, (float4*)abuf, N_NODES);

    gemmsegmax_kernel<<<(N_NODES + 63) / 64, 256, 0, stream>>>(abuf, W2, b2, gbuf, N_NODES);
    mlp_kernel<<<NGRAPH, 128, 0, stream>>>(gbuf, l1W, l1b, l2W, l2b, l3W, l3b, outp);
}